// Round 2
// baseline (1914.606 us; speedup 1.0000x reference)
//
#include <hip/hip_runtime.h>
#include <cstdint>
#include <cstddef>

// ---------------- problem constants ----------------
// B=32, ENC=512, P=196 (14x14), ATT=512, EMB=512, DEC=512, VOCAB=10000, T=63
typedef _Float16 f16;
typedef _Float16 h2 __attribute__((ext_vector_type(2)));
typedef _Float16 h8 __attribute__((ext_vector_type(8)));
typedef float f4v __attribute__((ext_vector_type(4)));

// ---------------- helpers ----------------
__device__ __forceinline__ h2 u2h2(unsigned u) { return __builtin_bit_cast(h2, u); }
__device__ __forceinline__ unsigned h22u(h2 v) { return __builtin_bit_cast(unsigned, v); }
__device__ __forceinline__ float2 u2f2(unsigned long long u) { return __builtin_bit_cast(float2, u); }

__device__ __forceinline__ float agent_ld_f(const float* p) {
    return __hip_atomic_load(p, __ATOMIC_RELAXED, __HIP_MEMORY_SCOPE_AGENT);
}
__device__ __forceinline__ void agent_st_f(float* p, float v) {
    __hip_atomic_store(p, v, __ATOMIC_RELAXED, __HIP_MEMORY_SCOPE_AGENT);
}
__device__ __forceinline__ unsigned agent_ld_u(const unsigned* p) {
    return __hip_atomic_load(p, __ATOMIC_RELAXED, __HIP_MEMORY_SCOPE_AGENT);
}
__device__ __forceinline__ void agent_st_u(unsigned* p, unsigned v) {
    __hip_atomic_store(p, v, __ATOMIC_RELAXED, __HIP_MEMORY_SCOPE_AGENT);
}
__device__ __forceinline__ unsigned long long agent_ld_u64(const unsigned long long* p) {
    return __hip_atomic_load(p, __ATOMIC_RELAXED, __HIP_MEMORY_SCOPE_AGENT);
}

__device__ __forceinline__ float fdot2(h2 a, h2 b, float c) {
#if __has_builtin(__builtin_amdgcn_fdot2)
    return __builtin_amdgcn_fdot2(a, b, c, false);
#else
    return c + (float)a.x * (float)b.x + (float)a.y * (float)b.y;
#endif
}
__device__ __forceinline__ float sigf(float x) { return 1.0f / (1.0f + expf(-x)); }

// per-group (32-block) all-to-all barrier. ALL-RELAXED atomics + compiler-only
// ordering (RELEASE/ACQUIRE would emit buffer_wbl2/buffer_inv and wipe L2
// weight residency). '>=' makes epoch-skew safe.
__device__ __forceinline__ void gbar32(unsigned* gflags, unsigned epoch, int local) {
    __syncthreads();
    if (threadIdx.x < 64) {
        if (threadIdx.x == 0) {
            asm volatile("s_waitcnt vmcnt(0)" ::: "memory");
            __hip_atomic_store(&gflags[local], epoch, __ATOMIC_RELAXED, __HIP_MEMORY_SCOPE_AGENT);
        }
        const int l = threadIdx.x & 31;
        bool ok;
        do {
            ok = (__hip_atomic_load(&gflags[l], __ATOMIC_RELAXED,
                                    __HIP_MEMORY_SCOPE_AGENT) >= epoch);
            if (!ok) __builtin_amdgcn_s_sleep(1);
        } while (__ballot(ok) != ~0ull);
        asm volatile("" ::: "memory");
    }
    __syncthreads();
}

// ---------------- prep: small weights / biases ----------------
__global__ void k_prep_w(const float* W_enc, const float* W_dec, const float* W_fb,
                         const float* b_dec, const float* b_fb,
                         const float* b_ih, const float* b_hh,
                         f16* W_encT, f16* Wdf8, float* b_df, float* b_cat) {
    const int S0 = 512 * 512;
    const int S2 = 512 * 1024;
    const int total = S0 + S2 + 1024 + 2048;
    for (int idx = blockIdx.x * 256 + threadIdx.x; idx < total; idx += gridDim.x * 256) {
        int i = idx;
        if (i < S0) { int n = i >> 9, k = i & 511; W_encT[i] = (f16)W_enc[k * 512 + n]; continue; }
        i -= S0;
        if (i < S2) {
            int k8 = i / 8192, r = i % 8192, col = r >> 3, kr = r & 7;
            int k = k8 * 8 + kr;
            float v = (col < 512) ? W_dec[k * 512 + col] : W_fb[k * 512 + (col - 512)];
            Wdf8[i] = (f16)v;
            continue;
        }
        i -= S2;
        if (i < 1024) { b_df[i] = (i < 512) ? b_dec[i] : b_fb[i - 512]; continue; }
        i -= 1024;
        b_cat[i] = b_ih[i] + b_hh[i];
    }
}

// ---------------- prep: tiled transpose W_fc -> W_fcT[n][k] fp16 ----------------
__global__ void k_tr_fc(const float* W_fc, f16* W_fcT) {
    __shared__ float tile[64][65];
    int n0 = blockIdx.x * 64;
    int k0 = blockIdx.y * 64;
    int t = threadIdx.x;
#pragma unroll
    for (int i = 0; i < 16; ++i) {
        int lin = t + i * 256;
        int kl = lin >> 6, nl = lin & 63;
        int n = n0 + nl;
        tile[kl][nl] = (n < 10000) ? W_fc[(long)(k0 + kl) * 10000 + n] : 0.0f;
    }
    __syncthreads();
#pragma unroll
    for (int i = 0; i < 2; ++i) {
        int lin = t + i * 256;
        int r = lin >> 3, cv = lin & 7;
        f16 v[8];
#pragma unroll
        for (int kr = 0; kr < 8; ++kr) v[kr] = (f16)tile[cv * 8 + kr][r];
        *(uint4*)&W_fcT[(long)(n0 + r) * 512 + k0 + cv * 8] = *(uint4*)v;
    }
}

// ---------------- prep: k8-repack [W_ih(top 512); W_hh] -> Wpart8 (K=1024) ----
__global__ void k_pack_part(const float* W_ih, const float* W_hh, f16* Wpart8) {
    __shared__ float tile[64][65];
    int k0 = blockIdx.x * 64;
    int n0 = blockIdx.y * 64;
    int t = threadIdx.x;
#pragma unroll
    for (int i = 0; i < 16; ++i) {
        int lin = t + i * 256;
        int kl = lin >> 6, nl = lin & 63;
        int k = k0 + kl;
        float v = (k < 512) ? W_ih[(long)k * 2048 + n0 + nl]
                            : W_hh[(long)(k - 512) * 2048 + n0 + nl];
        tile[kl][nl] = v;
    }
    __syncthreads();
#pragma unroll
    for (int i = 0; i < 2; ++i) {
        int lin = t + i * 256;
        int nl = lin & 63, k8l = lin >> 6;
        f16 v[8];
#pragma unroll
        for (int kr = 0; kr < 8; ++kr) v[kr] = (f16)tile[k8l * 8 + kr][nl];
        *(uint4*)&Wpart8[(long)(k0 / 8 + k8l) * 16384 + (long)(n0 + nl) * 8] = *(uint4*)v;
    }
}

// ---------------- prep: k8-repack W_ih(mid rows 512..1023) -> Wmid8 (K=512) ----------
__global__ void k_pack_mid(const float* W_ih, f16* Wmid8) {
    __shared__ float tile[64][65];
    int k0 = blockIdx.x * 64;
    int n0 = blockIdx.y * 64;
    int t = threadIdx.x;
#pragma unroll
    for (int i = 0; i < 16; ++i) {
        int lin = t + i * 256;
        int kl = lin >> 6, nl = lin & 63;
        tile[kl][nl] = W_ih[(long)(512 + k0 + kl) * 2048 + n0 + nl];
    }
    __syncthreads();
#pragma unroll
    for (int i = 0; i < 2; ++i) {
        int lin = t + i * 256;
        int nl = lin & 63, k8l = lin >> 6;
        f16 v[8];
#pragma unroll
        for (int kr = 0; kr < 8; ++kr) v[kr] = (f16)tile[k8l * 8 + kr][nl];
        *(uint4*)&Wmid8[(long)(k0 / 8 + k8l) * 16384 + (long)(n0 + nl) * 8] = *(uint4*)v;
    }
}

// ---------------- prep: enc transpose + mean ----------------
__global__ void k_prep_enc(const float* enc_out, f16* enc_t, float* mean_enc) {
    __shared__ float tile[64][197];
    int b = blockIdx.x >> 3, cc = blockIdx.x & 7, c0 = cc * 64;
    int t = threadIdx.x;
    const float* src = enc_out + ((long)b * 512 + c0) * 196;
    for (int i = 0; i < 49; ++i) {
        int lin = t + i * 256;
        int cl = lin / 196, p = lin % 196;
        tile[cl][p] = src[cl * 196 + p];
    }
    __syncthreads();
    if (t < 64) {
        float s = 0.f;
        for (int p = 0; p < 196; ++p) s += tile[t][p];
        mean_enc[b * 512 + c0 + t] = s * (1.0f / 196.0f);
    }
    __syncthreads();
    int cl = t & 63, pg = t >> 6;
    for (int i = 0; i < 49; ++i) {
        int p = pg * 49 + i;
        enc_t[((long)(b * 196 + p)) * 512 + c0 + cl] = (f16)tile[cl][p];
    }
}

// ---------------- h0/c0 + barrier/tail init ----------------
__global__ void k_h0c0(const float* mean_enc, const float* W_init_h, const float* b_init_h,
                       const float* W_init_c, const float* b_init_c,
                       float* c, f16* h_h, f16* h_all, unsigned* bar) {
    if (blockIdx.x == 64) {
        int t = threadIdx.x;
        for (int i = t; i < 512; i += 256) bar[i] = 0u;
        for (int i = t; i < 32 * 512; i += 256) h_all[(long)2016 * 512 + i] = (f16)0.0f;
        return;
    }
    __shared__ float ms[512];
    int b = blockIdx.x >> 1, which = blockIdx.x & 1;
    const float* W = which ? W_init_c : W_init_h;
    const float* bb = which ? b_init_c : b_init_h;
    int t = threadIdx.x;
    ms[t] = mean_enc[b * 512 + t];
    ms[t + 256] = mean_enc[b * 512 + t + 256];
    __syncthreads();
    for (int jj = 0; jj < 2; ++jj) {
        int j = t + jj * 256;
        float acc = bb[j];
        for (int k = 0; k < 512; ++k) acc += ms[k] * W[k * 512 + j];
        if (which) c[b * 512 + j] = acc;
        else h_h[b * 512 + j] = (f16)acc;
    }
}

// ---------------- enc_att = enc @ W_enc_att + b (fp16 MFMA) ----------------
__global__ __launch_bounds__(256, 2) void k_encatt(const f16* A, const f16* Bt,
                                                   const float* bias, f16* Cout) {
    __shared__ __align__(16) f16 As[128 * 32];
    __shared__ __align__(16) f16 Bs[128 * 32];
    int m0 = blockIdx.x * 128, n0 = blockIdx.y * 128;
    int t = threadIdx.x, w = t >> 6, lane = t & 63;
    int wm = (w >> 1) * 64, wn = (w & 1) * 64;
    int lm = lane & 15, lq = lane >> 4;
    f4v acc[4][4];
    for (int mi = 0; mi < 4; ++mi)
        for (int ni = 0; ni < 4; ++ni) acc[mi][ni] = (f4v){0.f, 0.f, 0.f, 0.f};
    for (int kb = 0; kb < 512; kb += 32) {
        for (int i = 0; i < 2; ++i) {
            int li = t + i * 256;
            int row = li >> 2, q = li & 3;
            *(uint4*)&As[row * 32 + q * 8] = *(const uint4*)&A[(long)(m0 + row) * 512 + kb + q * 8];
            *(uint4*)&Bs[row * 32 + q * 8] = *(const uint4*)&Bt[(long)(n0 + row) * 512 + kb + q * 8];
        }
        __syncthreads();
        h8 af[4], bf[4];
        for (int i = 0; i < 4; ++i) {
            af[i] = *(const h8*)&As[(wm + i * 16 + lm) * 32 + lq * 8];
            bf[i] = *(const h8*)&Bs[(wn + i * 16 + lm) * 32 + lq * 8];
        }
        for (int mi = 0; mi < 4; ++mi)
            for (int ni = 0; ni < 4; ++ni)
                acc[mi][ni] = __builtin_amdgcn_mfma_f32_16x16x32_f16(af[mi], bf[ni], acc[mi][ni], 0, 0, 0);
        __syncthreads();
    }
    for (int mi = 0; mi < 4; ++mi)
        for (int ni = 0; ni < 4; ++ni)
            for (int r = 0; r < 4; ++r) {
                int row = m0 + wm + mi * 16 + lq * 4 + r;
                int col = n0 + wn + ni * 16 + lm;
                Cout[(long)row * 512 + col] = (f16)(acc[mi][ni][r] + bias[col]);
            }
}

// ---------------- final FC: preds = h_all @ W_fc + b_fc (fp16 MFMA, masked) ----------------
__global__ __launch_bounds__(256, 2) void k_fc(const f16* A, const f16* Bt, const float* bias,
                                               const int* cl, float* out) {
    __shared__ __align__(16) f16 As[128 * 32];
    __shared__ __align__(16) f16 Bs[128 * 32];
    int m0 = blockIdx.x * 128, n0 = blockIdx.y * 128;
    int t = threadIdx.x, w = t >> 6, lane = t & 63;
    int wm = (w >> 1) * 64, wn = (w & 1) * 64;
    int lm = lane & 15, lq = lane >> 4;

    bool myact = false;
    if (t < 128) {
        int row = m0 + t;
        if (row < 2016) {
            int b = row / 63, tt = row - b * 63;
            myact = tt < (cl[b] - 1);
        }
    }
    int anyact = __syncthreads_or((int)myact);
    if (!anyact) {
        for (int i = 0; i < 64; ++i) {
            int idx = t + i * 256;
            int row = m0 + (idx >> 7), col = n0 + (idx & 127);
            if (row < 2016 && col < 10000) out[(long)row * 10000 + col] = 0.0f;
        }
        return;
    }

    f4v acc[4][4];
    for (int mi = 0; mi < 4; ++mi)
        for (int ni = 0; ni < 4; ++ni) acc[mi][ni] = (f4v){0.f, 0.f, 0.f, 0.f};
    for (int kb = 0; kb < 512; kb += 32) {
        for (int i = 0; i < 2; ++i) {
            int li = t + i * 256;
            int row = li >> 2, q = li & 3;
            *(uint4*)&As[row * 32 + q * 8] = *(const uint4*)&A[(long)(m0 + row) * 512 + kb + q * 8];
            *(uint4*)&Bs[row * 32 + q * 8] = *(const uint4*)&Bt[(long)(n0 + row) * 512 + kb + q * 8];
        }
        __syncthreads();
        h8 af[4], bf[4];
        for (int i = 0; i < 4; ++i) {
            af[i] = *(const h8*)&As[(wm + i * 16 + lm) * 32 + lq * 8];
            bf[i] = *(const h8*)&Bs[(wn + i * 16 + lm) * 32 + lq * 8];
        }
        for (int mi = 0; mi < 4; ++mi)
            for (int ni = 0; ni < 4; ++ni)
                acc[mi][ni] = __builtin_amdgcn_mfma_f32_16x16x32_f16(af[mi], bf[ni], acc[mi][ni], 0, 0, 0);
        __syncthreads();
    }
    for (int mi = 0; mi < 4; ++mi)
        for (int ni = 0; ni < 4; ++ni)
            for (int r = 0; r < 4; ++r) {
                int row = m0 + wm + mi * 16 + lq * 4 + r;
                int col = n0 + wn + ni * 16 + lm;
                if (row < 2016 && col < 10000) {
                    int b = row / 63, tt = row - b * 63;
                    bool act = tt < (cl[b] - 1);
                    out[(long)row * 10000 + col] = act ? (acc[mi][ni][r] + bias[col]) : 0.0f;
                }
            }
}

// ---------------- persistent recurrent loop (3 barriers/step, 512-thread blocks) ------
// 8 INDEPENDENT groups of 32 blocks; group g owns batches g*4..g*4+3; group-local
// gbar32 barriers. New this round:
//  - enc_att / enc_t 25-row slices are step-invariant per block -> staged in LDS
//    once (P2 becomes: 1 LLC load of da + pure-LDS compute).
//  - emb-half of the gate GEMV (waves 0..3, k8 0..63) is h-independent -> runs
//    as "prework" before gbar(3) of the previous step, overlapping barrier skew.
//    Post-barrier P1: h staging + waves 4..7 gate h-half + waves 0..3 df GEMV.
//  - early group exit at steps_g = max(cl[group])-1 (lens sorted desc); inactive
//    h_all rows are masked to 0 by k_fc so their content is irrelevant.
__global__ __launch_bounds__(512, 2) void k_loop(
    const f16* Wdf8, const float* b_df,
    const f16* Wpart8, const f16* Wmid8, const float* b_cat,
    const f16* enc_att_h, const f16* enc_t,
    const float* W_full, const float* emb, const int* caps, const int* cl,
    float* c, f16* h_h, float* da_gp, float* gp_part, float* pawe, float* psum,
    f16* h_all, unsigned* bar) {
    __shared__ __align__(16) unsigned xcat[4 * 512];   // [emb|h] f16x2 (8 KB)
    __shared__ float gred[8 * 4 * 64];                 // gate K-eighth partials
    __shared__ float dfred[256];                       // P1 df partials (2 per col)
    __shared__ float das2[512];                        // P2 dec_a
    __shared__ float es[32];                           // P2 exp(scores)
    __shared__ float ps4[4];                           // P3 1/sum(exp)
    __shared__ __align__(16) unsigned xms[4 * 256];    // P3 gated awe f16x2 (4 KB)
    __shared__ float g3[8 * 4 * 64];                   // P3 K-eighth partials
    __shared__ float gsm[256];                         // P3 gate values
    __shared__ __align__(16) f16 ea_s[25 * 512];       // staged enc_att slice (25.6 KB)
    __shared__ __align__(16) f16 et_s[512 * 26];       // staged enc_t slice, transposed (26.6 KB)

    const int bid = blockIdx.x, t = threadIdx.x;
    const int lane = t & 63, w = t >> 6;
    const int local = bid & 31;
    unsigned* gflags = bar + (bid >> 5) * 32;          // per-group flag line (128 B)

    const int bg = bid >> 5, b0 = bg * 4;
    const int cg = bid & 31;            // P1 colgroup
    const int jg = bid & 31;            // P3 jgroup
    // P2: group-local mapping — batch within group, 8 p-groups per batch
    const int b2 = b0 + ((bid >> 3) & 3), pg = bid & 7;
    const int nr = (196 - pg * 25) < 25 ? (196 - pg * 25) : 25;

    // step-invariant preloads
    float4 wfa = *(const float4*)(W_full + lane * 8);
    float4 wfb = *(const float4*)(W_full + lane * 8 + 4);
    float bc_g = 0.f, bdf = 0.f;
    if (t < 256) bc_g = b_cat[cg * 64 + (t & 63)];
    if (t < 128) bdf = b_df[cg * 32 + (t & 31)];
    const int nc3 = ((t & 63) >> 4) * 512 + jg * 16 + (t & 15);  // P3 combine col (t<256)
    const int myb = b0 + (t >> 3);
    const int mycl = (t < 32) ? cl[myb] : 0;
    const int jp = t & 7;
    const int j0 = jg * 16 + jp * 2;
    const int n1 = cg * 64 + lane;                                // P1 gate col
    const int n3 = (lane >> 4) * 512 + jg * 16 + (lane & 15);     // P3 gate col

    // group trip count (caption_lengths sorted desc; take max of 4 for safety)
    int steps_g;
    {
        int c0v = cl[b0], c1v = cl[b0 + 1], c2v = cl[b0 + 2], c3v = cl[b0 + 3];
        int m01 = c0v > c1v ? c0v : c1v;
        int m23 = c2v > c3v ? c2v : c3v;
        steps_g = (m01 > m23 ? m01 : m23) - 1;
    }

    // ---- stage step-invariant P2 slices into LDS (once) ----
    {
        int r = t >> 6, cv = t & 63;   // wave-uniform row, lane = 8-f16 chunk
        for (int base = 0; base < 25; base += 8) {
            int rr = base + r;
            if (rr < nr) {
                const long rowoff = ((long)b2 * 196 + pg * 25 + rr) * 512 + cv * 8;
                uint4 va = *(const uint4*)(enc_att_h + rowoff);
                *(uint4*)&ea_s[rr * 512 + cv * 8] = va;
                uint4 vt = *(const uint4*)(enc_t + rowoff);
                f16 tmp[8]; *(uint4*)tmp = vt;
#pragma unroll
                for (int e = 0; e < 8; ++e) et_s[(cv * 8 + e) * 26 + rr] = tmp[e];
            }
        }
    }

    // ---- prework(s): stage emb for step s; waves 0..3 run emb-half gate GEMV ----
    auto prework = [&](int sstep) {
#pragma unroll
        for (int i = 0; i < 2; ++i) {
            int idx = t + i * 512;
            int b = idx >> 8, off = idx & 255;
            int tok = caps[(b0 + b) * 64 + sstep];
            float2 ev = *(const float2*)(emb + (long)tok * 512 + off * 2);
            h2 pe; pe.x = (f16)ev.x; pe.y = (f16)ev.y;
            xcat[b * 512 + off] = h22u(pe);
        }
        __syncthreads();
        if (w < 4) {
            const f16* wp = Wpart8 + (long)n1 * 8;
            float a0 = 0.f, a1 = 0.f, a2 = 0.f, a3 = 0.f;
            for (int kk = 0; kk < 16; ++kk) {
                int k8 = w * 16 + kk;   // 0..63 = emb K-range
                uint4 wv = *(const uint4*)(wp + (long)k8 * 16384);
                uint4 x0 = *(const uint4*)&xcat[0 * 512 + k8 * 4];
                uint4 x1 = *(const uint4*)&xcat[1 * 512 + k8 * 4];
                uint4 x2 = *(const uint4*)&xcat[2 * 512 + k8 * 4];
                uint4 x3 = *(const uint4*)&xcat[3 * 512 + k8 * 4];
                a0 = fdot2(u2h2(x0.x), u2h2(wv.x), a0);
                a0 = fdot2(u2h2(x0.y), u2h2(wv.y), a0);
                a0 = fdot2(u2h2(x0.z), u2h2(wv.z), a0);
                a0 = fdot2(u2h2(x0.w), u2h2(wv.w), a0);
                a1 = fdot2(u2h2(x1.x), u2h2(wv.x), a1);
                a1 = fdot2(u2h2(x1.y), u2h2(wv.y), a1);
                a1 = fdot2(u2h2(x1.z), u2h2(wv.z), a1);
                a1 = fdot2(u2h2(x1.w), u2h2(wv.w), a1);
                a2 = fdot2(u2h2(x2.x), u2h2(wv.x), a2);
                a2 = fdot2(u2h2(x2.y), u2h2(wv.y), a2);
                a2 = fdot2(u2h2(x2.z), u2h2(wv.z), a2);
                a2 = fdot2(u2h2(x2.w), u2h2(wv.w), a2);
                a3 = fdot2(u2h2(x3.x), u2h2(wv.x), a3);
                a3 = fdot2(u2h2(x3.y), u2h2(wv.y), a3);
                a3 = fdot2(u2h2(x3.z), u2h2(wv.z), a3);
                a3 = fdot2(u2h2(x3.w), u2h2(wv.w), a3);
            }
            gred[(w * 4 + 0) * 64 + lane] = a0;
            gred[(w * 4 + 1) * 64 + lane] = a1;
            gred[(w * 4 + 2) * 64 + lane] = a2;
            gred[(w * 4 + 3) * 64 + lane] = a3;
        }
    };

    prework(0);

    for (int step = 0; step < steps_g; ++step) {
        // ================= P1 (post-barrier part) =================
        {
#pragma unroll
            for (int i = 0; i < 2; ++i) {
                int idx = t + i * 512;
                int b = idx >> 8, off = idx & 255;
                xcat[b * 512 + 256 + off] = agent_ld_u((const unsigned*)h_h + (b0 + b) * 256 + off);
            }
            __syncthreads();
            if (w >= 4) {
                // gate GEMV h-half: k8 64..127, 4 batches per lane
                const f16* wp = Wpart8 + (long)n1 * 8;
                float a0 = 0.f, a1 = 0.f, a2 = 0.f, a3 = 0.f;
                for (int kk = 0; kk < 16; ++kk) {
                    int k8 = w * 16 + kk;   // 64..127 = h K-range
                    uint4 wv = *(const uint4*)(wp + (long)k8 * 16384);
                    uint4 x0 = *(const uint4*)&xcat[0 * 512 + k8 * 4];
                    uint4 x1 = *(const uint4*)&xcat[1 * 512 + k8 * 4];
                    uint4 x2 = *(const uint4*)&xcat[2 * 512 + k8 * 4];
                    uint4 x3 = *(const uint4*)&xcat[3 * 512 + k8 * 4];
                    a0 = fdot2(u2h2(x0.x), u2h2(wv.x), a0);
                    a0 = fdot2(u2h2(x0.y), u2h2(wv.y), a0);
                    a0 = fdot2(u2h2(x0.z), u2h2(wv.z), a0);
                    a0 = fdot2(u2h2(x0.w), u2h2(wv.w), a0);
                    a1 = fdot2(u2h2(x1.x), u2h2(wv.x), a1);
                    a1 = fdot2(u2h2(x1.y), u2h2(wv.y), a1);
                    a1 = fdot2(u2h2(x1.z), u2h2(wv.z), a1);
                    a1 = fdot2(u2h2(x1.w), u2h2(wv.w), a1);
                    a2 = fdot2(u2h2(x2.x), u2h2(wv.x), a2);
                    a2 = fdot2(u2h2(x2.y), u2h2(wv.y), a2);
                    a2 = fdot2(u2h2(x2.z), u2h2(wv.z), a2);
                    a2 = fdot2(u2h2(x2.w), u2h2(wv.w), a2);
                    a3 = fdot2(u2h2(x3.x), u2h2(wv.x), a3);
                    a3 = fdot2(u2h2(x3.y), u2h2(wv.y), a3);
                    a3 = fdot2(u2h2(x3.z), u2h2(wv.z), a3);
                    a3 = fdot2(u2h2(x3.w), u2h2(wv.w), a3);
                }
                gred[(w * 4 + 0) * 64 + lane] = a0;
                gred[(w * 4 + 1) * 64 + lane] = a1;
                gred[(w * 4 + 2) * 64 + lane] = a2;
                gred[(w * 4 + 3) * 64 + lane] = a3;
            } else {
                // dec/f_beta GEMV: wave = batch (0..3); lane -> col (32), K-half
                const int dfc = cg * 32 + (lane & 31);
                const f16* wdf = Wdf8 + (long)dfc * 8;
                const unsigned* hx = &xcat[w * 512 + 256];
                int kbase = (lane >> 5) * 32;
                float a = 0.f;
                for (int kk = 0; kk < 32; ++kk) {
                    int k8 = kbase + kk;
                    uint4 wv = *(const uint4*)(wdf + (long)k8 * 8192);
                    uint4 xv = *(const uint4*)&hx[k8 * 4];
                    a = fdot2(u2h2(xv.x), u2h2(wv.x), a);
                    a = fdot2(u2h2(xv.y), u2h2(wv.y), a);
                    a = fdot2(u2h2(xv.z), u2h2(wv.z), a);
                    a = fdot2(u2h2(xv.w), u2h2(wv.w), a);
                }
                dfred[(w * 32 + (lane & 31)) * 2 + (lane >> 5)] = a;
            }
            __syncthreads();
            if (t < 256) {
                int b = t >> 6, col = t & 63;
                float v = bc_g;
#pragma unroll
                for (int ww = 0; ww < 8; ++ww) v += gred[(ww * 4 + b) * 64 + col];
                agent_st_f(gp_part + (long)(b0 + b) * 2048 + cg * 64 + col, v);
            }
            if (t < 128) {
                int b = t >> 5, col = t & 31;
                const float* dr = &dfred[(b * 32 + col) * 2];
                float v = dr[0] + dr[1] + bdf;
                agent_st_f(da_gp + (long)(b0 + b) * 1024 + cg * 32 + col, v);
            }
        }
        gbar32(gflags, (unsigned)step * 3u + 1u, local);

        // ================= P2: scores + exp + partial weighted sums (LDS-staged) ========
        {
            das2[t] = agent_ld_f(da_gp + (long)b2 * 1024 + t);
            __syncthreads();
            float4 dv0 = *(const float4*)&das2[lane * 8];
            float4 dv1 = *(const float4*)&das2[lane * 8 + 4];
#pragma unroll
            for (int i = 0; i < 4; ++i) {
                int r = w + i * 8;
                if (r < nr) {
                    uint4 ev = *(const uint4*)&ea_s[r * 512 + lane * 8];
                    h2 e0 = u2h2(ev.x), e1 = u2h2(ev.y), e2 = u2h2(ev.z), e3 = u2h2(ev.w);
                    float a = 0.f;
                    a += fmaxf((float)e0.x + dv0.x, 0.f) * wfa.x;
                    a += fmaxf((float)e0.y + dv0.y, 0.f) * wfa.y;
                    a += fmaxf((float)e1.x + dv0.z, 0.f) * wfa.z;
                    a += fmaxf((float)e1.y + dv0.w, 0.f) * wfa.w;
                    a += fmaxf((float)e2.x + dv1.x, 0.f) * wfb.x;
                    a += fmaxf((float)e2.y + dv1.y, 0.f) * wfb.y;
                    a += fmaxf((float)e3.x + dv1.z, 0.f) * wfb.z;
                    a += fmaxf((float)e3.y + dv1.w, 0.f) * wfb.w;
                    for (int m = 32; m; m >>= 1) a += __shfl_xor(a, m);
                    if (lane == 0) es[r] = expf(a);
                }
            }
            __syncthreads();
            {
                float acc = 0.f;
                for (int r = 0; r < nr; ++r) acc += es[r] * (float)et_s[t * 26 + r];
                agent_st_f(pawe + ((long)b2 * 8 + pg) * 512 + t, acc);
                if (t == 0) {
                    float s = 0.f;
                    for (int r = 0; r < nr; ++r) s += es[r];
                    agent_st_f(psum + b2 * 8 + pg, s);
                }
            }
        }
        gbar32(gflags, (unsigned)step * 3u + 2u, local);

        // ================= P3 =================
        {
            float vpart = 0.f;
            if (t < 256) vpart = agent_ld_f(gp_part + (long)(b0 + (t >> 6)) * 2048 + nc3);
            if (t < 4) {
                float s = 0.f;
#pragma unroll
                for (int pgi = 0; pgi < 8; ++pgi)
                    s += agent_ld_f(psum + (b0 + t) * 8 + pgi);
                ps4[t] = 1.0f / s;
            }
            __syncthreads();
#pragma unroll
            for (int i = 0; i < 2; ++i) {
                int idx = t + i * 512;             // 0..1023 = 4 b x 256 c-pairs
                int bb = idx >> 8, cp = idx & 255;
                float sx = 0.f, sy = 0.f;
#pragma unroll
                for (int pgi = 0; pgi < 8; ++pgi) {
                    float2 v = u2f2(agent_ld_u64(
                        (const unsigned long long*)pawe + ((long)(b0 + bb) * 8 + pgi) * 256 + cp));
                    sx += v.x; sy += v.y;
                }
                float inv = ps4[bb];
                float2 fb = u2f2(agent_ld_u64(
                    (const unsigned long long*)da_gp + (long)(b0 + bb) * 512 + 256 + cp));
                h2 pa;
                pa.x = (f16)(sigf(fb.x) * sx * inv);
                pa.y = (f16)(sigf(fb.y) * sy * inv);
                xms[bb * 256 + cp] = h22u(pa);
            }
            __syncthreads();
            // mid-GEMM: wave -> K-eighth (8 k8), 4 batches per lane
            {
                const f16* wp = Wmid8 + (long)n3 * 8;
                float a0 = 0.f, a1 = 0.f, a2 = 0.f, a3 = 0.f;
                for (int kk = 0; kk < 8; ++kk) {
                    int k8 = w * 8 + kk;
                    uint4 wv = *(const uint4*)(wp + (long)k8 * 16384);
                    uint4 x0 = *(const uint4*)&xms[0 * 256 + k8 * 4];
                    uint4 x1 = *(const uint4*)&xms[1 * 256 + k8 * 4];
                    uint4 x2 = *(const uint4*)&xms[2 * 256 + k8 * 4];
                    uint4 x3 = *(const uint4*)&xms[3 * 256 + k8 * 4];
                    a0 = fdot2(u2h2(x0.x), u2h2(wv.x), a0);
                    a0 = fdot2(u2h2(x0.y), u2h2(wv.y), a0);
                    a0 = fdot2(u2h2(x0.z), u2h2(wv.z), a0);
                    a0 = fdot2(u2h2(x0.w), u2h2(wv.w), a0);
                    a1 = fdot2(u2h2(x1.x), u2h2(wv.x), a1);
                    a1 = fdot2(u2h2(x1.y), u2h2(wv.y), a1);
                    a1 = fdot2(u2h2(x1.z), u2h2(wv.z), a1);
                    a1 = fdot2(u2h2(x1.w), u2h2(wv.w), a1);
                    a2 = fdot2(u2h2(x2.x), u2h2(wv.x), a2);
                    a2 = fdot2(u2h2(x2.y), u2h2(wv.y), a2);
                    a2 = fdot2(u2h2(x2.z), u2h2(wv.z), a2);
                    a2 = fdot2(u2h2(x2.w), u2h2(wv.w), a2);
                    a3 = fdot2(u2h2(x3.x), u2h2(wv.x), a3);
                    a3 = fdot2(u2h2(x3.y), u2h2(wv.y), a3);
                    a3 = fdot2(u2h2(x3.z), u2h2(wv.z), a3);
                    a3 = fdot2(u2h2(x3.w), u2h2(wv.w), a3);
                }
                g3[(w * 4 + 0) * 64 + lane] = a0;
                g3[(w * 4 + 1) * 64 + lane] = a1;
                g3[(w * 4 + 2) * 64 + lane] = a2;
                g3[(w * 4 + 3) * 64 + lane] = a3;
            }
            __syncthreads();
            if (t < 256) {
                int b = t >> 6, l2 = t & 63;
                float v = vpart;
#pragma unroll
                for (int ww = 0; ww < 8; ++ww) v += g3[(ww * 4 + b) * 64 + l2];
                gsm[b * 64 + l2] = v;
            }
            __syncthreads();
            if (t < 32) {
                int bl = t >> 3;
                int l0 = jp * 2, l1 = jp * 2 + 1;
                float gi0 = gsm[bl * 64 + l0],      gi1 = gsm[bl * 64 + l1];
                float gf0 = gsm[bl * 64 + 16 + l0], gf1 = gsm[bl * 64 + 16 + l1];
                float gg0 = gsm[bl * 64 + 32 + l0], gg1 = gsm[bl * 64 + 32 + l1];
                float go0 = gsm[bl * 64 + 48 + l0], go1 = gsm[bl * 64 + 48 + l1];
                float2 cold = *(float2*)(c + (long)myb * 512 + j0);
                float cn0 = sigf(gf0) * cold.x + sigf(gi0) * tanhf(gg0);
                float hn0 = sigf(go0) * tanhf(cn0);
                float cn1 = sigf(gf1) * cold.y + sigf(gi1) * tanhf(gg1);
                float hn1 = sigf(go1) * tanhf(cn1);
                h2 oldh = u2h2(agent_ld_u((const unsigned*)h_h + myb * 256 + (j0 >> 1)));
                bool act = step < (mycl - 1);
                float hv0, hv1, cv0, cv1;
                if (act) { hv0 = hn0; hv1 = hn1; cv0 = cn0; cv1 = cn1; }
                else { hv0 = (float)oldh.x; hv1 = (float)oldh.y; cv0 = cold.x; cv1 = cold.y; }
                float2 cw; cw.x = cv0; cw.y = cv1;
                *(float2*)(c + (long)myb * 512 + j0) = cw;
                h2 hp; hp.x = (f16)hv0; hp.y = (f16)hv1;
                unsigned pv = h22u(hp);
                agent_st_u((unsigned*)h_h + myb * 256 + (j0 >> 1), pv);
                *((unsigned*)h_all + ((long)myb * 63 + step) * 256 + (j0 >> 1)) = pv;
            }
            // prework for step+1 overlaps the coming barrier skew
            prework(step + 1);
        }
        gbar32(gflags, (unsigned)step * 3u + 3u, local);
    }
}

// ---------------- launcher ----------------
extern "C" void kernel_launch(void* const* d_in, const int* in_sizes, int n_in,
                              void* d_out, int out_size, void* d_ws, size_t ws_size,
                              hipStream_t stream) {
    const float* encoder_out = (const float*)d_in[0];
    const int* caps = (const int*)d_in[1];
    const int* cl = (const int*)d_in[2];
    const float* emb = (const float*)d_in[3];
    const float* W_enc_att = (const float*)d_in[4];
    const float* b_enc_att = (const float*)d_in[5];
    const float* W_dec_att = (const float*)d_in[6];
    const float* b_dec_att = (const float*)d_in[7];
    const float* W_full_att = (const float*)d_in[8];
    const float* W_init_h = (const float*)d_in[10];
    const float* b_init_h = (const float*)d_in[11];
    const float* W_init_c = (const float*)d_in[12];
    const float* b_init_c = (const float*)d_in[13];
    const float* W_f_beta = (const float*)d_in[14];
    const float* b_f_beta = (const float*)d_in[15];
    const float* W_ih = (const float*)d_in[16];
    const float* b_ih = (const float*)d_in[17];
    const float* W_hh = (const float*)d_in[18];
    const float* b_hh = (const float*)d_in[19];
    const float* W_fc = (const float*)d_in[20];
    const float* b_fc = (const float*)d_in[21];

    char* p = (char*)d_ws;
    auto take = [&](size_t bytes) {
        char* r = p;
        p += (bytes + 255) & ~(size_t)255;
        return r;
    };
    f16* enc_t     = (f16*)take((size_t)32 * 196 * 512 * 2);
    f16* enc_att_h = (f16*)take((size_t)32 * 196 * 512 * 2);
    f16* W_encT    = (f16*)take((size_t)512 * 512 * 2);
    f16* W_fcT     = (f16*)take((size_t)10112 * 512 * 2);
    f16* Wdf8      = (f16*)take((size_t)512 * 1024 * 2);
    f16* Wpart8    = (f16*)take((size_t)1024 * 2048 * 2);
    f16* Wmid8     = (f16*)take((size_t)512 * 2048 * 2);
    f16* h_all     = (f16*)take((size_t)2048 * 512 * 2);
    f16* h_h       = (f16*)take((size_t)32 * 512 * 2);
    float* b_df    = (float*)take(1024 * 4);
    float* b_cat   = (float*)take(2048 * 4);
    float* mean_e  = (float*)take((size_t)32 * 512 * 4);
    float* c_st    = (float*)take((size_t)32 * 512 * 4);
    float* da_gp   = (float*)take((size_t)32 * 1024 * 4);
    float* gp_part = (float*)take((size_t)32 * 2048 * 4);
    float* pawe    = (float*)take((size_t)32 * 8 * 512 * 4);
    float* psum    = (float*)take((size_t)256 * 4);
    unsigned* bar  = (unsigned*)take(2048);

    k_prep_w<<<1024, 256, 0, stream>>>(W_enc_att, W_dec_att, W_f_beta,
                                       b_dec_att, b_f_beta, b_ih, b_hh,
                                       W_encT, Wdf8, b_df, b_cat);
    k_tr_fc<<<dim3(158, 8), 256, 0, stream>>>(W_fc, W_fcT);
    k_pack_part<<<dim3(16, 32), 256, 0, stream>>>(W_ih, W_hh, Wpart8);
    k_pack_mid<<<dim3(8, 32), 256, 0, stream>>>(W_ih, Wmid8);
    k_prep_enc<<<256, 256, 0, stream>>>(encoder_out, enc_t, mean_e);
    k_h0c0<<<65, 256, 0, stream>>>(mean_e, W_init_h, b_init_h, W_init_c, b_init_c,
                                   c_st, h_h, h_all, bar);
    k_encatt<<<dim3(49, 4), 256, 0, stream>>>(enc_t, W_encT, b_enc_att, enc_att_h);
    k_loop<<<256, 512, 0, stream>>>(Wdf8, b_df, Wpart8, Wmid8, b_cat,
                                    enc_att_h, enc_t, W_full_att, emb, caps, cl,
                                    c_st, h_h, da_gp, gp_part, pawe, psum, h_all, bar);
    k_fc<<<dim3(16, 79), 256, 0, stream>>>(h_all, W_fcT, b_fc, cl, (float*)d_out);
}

// Round 3
// 1616.303 us; speedup vs baseline: 1.1846x; 1.1846x over previous
//
#include <hip/hip_runtime.h>
#include <cstdint>
#include <cstddef>

// ---------------- problem constants ----------------
// B=32, ENC=512, P=196 (14x14), ATT=512, EMB=512, DEC=512, VOCAB=10000, T=63
typedef _Float16 f16;
typedef _Float16 h2 __attribute__((ext_vector_type(2)));
typedef _Float16 h8 __attribute__((ext_vector_type(8)));
typedef float f4v __attribute__((ext_vector_type(4)));

// ---------------- helpers ----------------
__device__ __forceinline__ h2 u2h2(unsigned u) { return __builtin_bit_cast(h2, u); }
__device__ __forceinline__ unsigned h22u(h2 v) { return __builtin_bit_cast(unsigned, v); }
__device__ __forceinline__ float2 u2f2(unsigned long long u) { return __builtin_bit_cast(float2, u); }

__device__ __forceinline__ float agent_ld_f(const float* p) {
    return __hip_atomic_load(p, __ATOMIC_RELAXED, __HIP_MEMORY_SCOPE_AGENT);
}
__device__ __forceinline__ void agent_st_f(float* p, float v) {
    __hip_atomic_store(p, v, __ATOMIC_RELAXED, __HIP_MEMORY_SCOPE_AGENT);
}
__device__ __forceinline__ void agent_add_f(float* p, float v) {
    __hip_atomic_fetch_add(p, v, __ATOMIC_RELAXED, __HIP_MEMORY_SCOPE_AGENT);
}
__device__ __forceinline__ unsigned agent_ld_u(const unsigned* p) {
    return __hip_atomic_load(p, __ATOMIC_RELAXED, __HIP_MEMORY_SCOPE_AGENT);
}
__device__ __forceinline__ void agent_st_u(unsigned* p, unsigned v) {
    __hip_atomic_store(p, v, __ATOMIC_RELAXED, __HIP_MEMORY_SCOPE_AGENT);
}
__device__ __forceinline__ unsigned long long agent_ld_u64(const unsigned long long* p) {
    return __hip_atomic_load(p, __ATOMIC_RELAXED, __HIP_MEMORY_SCOPE_AGENT);
}

__device__ __forceinline__ float fdot2(h2 a, h2 b, float c) {
#if __has_builtin(__builtin_amdgcn_fdot2)
    return __builtin_amdgcn_fdot2(a, b, c, false);
#else
    return c + (float)a.x * (float)b.x + (float)a.y * (float)b.y;
#endif
}
__device__ __forceinline__ float sigf(float x) { return 1.0f / (1.0f + expf(-x)); }

// per-group (32-block) all-to-all barrier. ALL-RELAXED atomics + compiler-only
// ordering (RELEASE/ACQUIRE would emit buffer_wbl2/buffer_inv and wipe L2
// weight residency). '>=' makes epoch-skew safe.
__device__ __forceinline__ void gbar32(unsigned* gflags, unsigned epoch, int local) {
    __syncthreads();
    if (threadIdx.x < 64) {
        if (threadIdx.x == 0) {
            asm volatile("s_waitcnt vmcnt(0)" ::: "memory");
            __hip_atomic_store(&gflags[local], epoch, __ATOMIC_RELAXED, __HIP_MEMORY_SCOPE_AGENT);
        }
        const int l = threadIdx.x & 31;
        bool ok;
        do {
            ok = (__hip_atomic_load(&gflags[l], __ATOMIC_RELAXED,
                                    __HIP_MEMORY_SCOPE_AGENT) >= epoch);
            if (!ok) __builtin_amdgcn_s_sleep(1);
        } while (__ballot(ok) != ~0ull);
        asm volatile("" ::: "memory");
    }
    __syncthreads();
}

// ---------------- prep: small weights / biases ----------------
__global__ void k_prep_w(const float* W_enc, const float* W_dec, const float* W_fb,
                         const float* b_dec, const float* b_fb,
                         const float* b_ih, const float* b_hh,
                         f16* W_encT, f16* Wdf8, float* b_df, float* b_cat) {
    const int S0 = 512 * 512;
    const int S2 = 512 * 1024;
    const int total = S0 + S2 + 1024 + 2048;
    for (int idx = blockIdx.x * 256 + threadIdx.x; idx < total; idx += gridDim.x * 256) {
        int i = idx;
        if (i < S0) { int n = i >> 9, k = i & 511; W_encT[i] = (f16)W_enc[k * 512 + n]; continue; }
        i -= S0;
        if (i < S2) {
            int k8 = i / 8192, r = i % 8192, col = r >> 3, kr = r & 7;
            int k = k8 * 8 + kr;
            float v = (col < 512) ? W_dec[k * 512 + col] : W_fb[k * 512 + (col - 512)];
            Wdf8[i] = (f16)v;
            continue;
        }
        i -= S2;
        if (i < 1024) { b_df[i] = (i < 512) ? b_dec[i] : b_fb[i - 512]; continue; }
        i -= 1024;
        b_cat[i] = b_ih[i] + b_hh[i];
    }
}

// ---------------- prep: tiled transpose W_fc -> W_fcT[n][k] fp16 ----------------
__global__ void k_tr_fc(const float* W_fc, f16* W_fcT) {
    __shared__ float tile[64][65];
    int n0 = blockIdx.x * 64;
    int k0 = blockIdx.y * 64;
    int t = threadIdx.x;
#pragma unroll
    for (int i = 0; i < 16; ++i) {
        int lin = t + i * 256;
        int kl = lin >> 6, nl = lin & 63;
        int n = n0 + nl;
        tile[kl][nl] = (n < 10000) ? W_fc[(long)(k0 + kl) * 10000 + n] : 0.0f;
    }
    __syncthreads();
#pragma unroll
    for (int i = 0; i < 2; ++i) {
        int lin = t + i * 256;
        int r = lin >> 3, cv = lin & 7;
        f16 v[8];
#pragma unroll
        for (int kr = 0; kr < 8; ++kr) v[kr] = (f16)tile[cv * 8 + kr][r];
        *(uint4*)&W_fcT[(long)(n0 + r) * 512 + k0 + cv * 8] = *(uint4*)v;
    }
}

// ---------------- prep: k8-repack [W_ih(top 512); W_hh] -> Wpart8 (K=1024) ----
__global__ void k_pack_part(const float* W_ih, const float* W_hh, f16* Wpart8) {
    __shared__ float tile[64][65];
    int k0 = blockIdx.x * 64;
    int n0 = blockIdx.y * 64;
    int t = threadIdx.x;
#pragma unroll
    for (int i = 0; i < 16; ++i) {
        int lin = t + i * 256;
        int kl = lin >> 6, nl = lin & 63;
        int k = k0 + kl;
        float v = (k < 512) ? W_ih[(long)k * 2048 + n0 + nl]
                            : W_hh[(long)(k - 512) * 2048 + n0 + nl];
        tile[kl][nl] = v;
    }
    __syncthreads();
#pragma unroll
    for (int i = 0; i < 2; ++i) {
        int lin = t + i * 256;
        int nl = lin & 63, k8l = lin >> 6;
        f16 v[8];
#pragma unroll
        for (int kr = 0; kr < 8; ++kr) v[kr] = (f16)tile[k8l * 8 + kr][nl];
        *(uint4*)&Wpart8[(long)(k0 / 8 + k8l) * 16384 + (long)(n0 + nl) * 8] = *(uint4*)v;
    }
}

// ---------------- prep: k8-repack W_ih(mid rows 512..1023) -> Wmid8 (K=512) ----------
__global__ void k_pack_mid(const float* W_ih, f16* Wmid8) {
    __shared__ float tile[64][65];
    int k0 = blockIdx.x * 64;
    int n0 = blockIdx.y * 64;
    int t = threadIdx.x;
#pragma unroll
    for (int i = 0; i < 16; ++i) {
        int lin = t + i * 256;
        int kl = lin >> 6, nl = lin & 63;
        tile[kl][nl] = W_ih[(long)(512 + k0 + kl) * 2048 + n0 + nl];
    }
    __syncthreads();
#pragma unroll
    for (int i = 0; i < 2; ++i) {
        int lin = t + i * 256;
        int nl = lin & 63, k8l = lin >> 6;
        f16 v[8];
#pragma unroll
        for (int kr = 0; kr < 8; ++kr) v[kr] = (f16)tile[k8l * 8 + kr][nl];
        *(uint4*)&Wmid8[(long)(k0 / 8 + k8l) * 16384 + (long)(n0 + nl) * 8] = *(uint4*)v;
    }
}

// ---------------- prep: enc transpose + mean ----------------
__global__ void k_prep_enc(const float* enc_out, f16* enc_t, float* mean_enc) {
    __shared__ float tile[64][197];
    int b = blockIdx.x >> 3, cc = blockIdx.x & 7, c0 = cc * 64;
    int t = threadIdx.x;
    const float* src = enc_out + ((long)b * 512 + c0) * 196;
    for (int i = 0; i < 49; ++i) {
        int lin = t + i * 256;
        int cl = lin / 196, p = lin % 196;
        tile[cl][p] = src[cl * 196 + p];
    }
    __syncthreads();
    if (t < 64) {
        float s = 0.f;
        for (int p = 0; p < 196; ++p) s += tile[t][p];
        mean_enc[b * 512 + c0 + t] = s * (1.0f / 196.0f);
    }
    __syncthreads();
    int cl = t & 63, pg = t >> 6;
    for (int i = 0; i < 49; ++i) {
        int p = pg * 49 + i;
        enc_t[((long)(b * 196 + p)) * 512 + c0 + cl] = (f16)tile[cl][p];
    }
}

// ---------------- h0/c0 + barrier/tail init ----------------
__global__ void k_h0c0(const float* mean_enc, const float* W_init_h, const float* b_init_h,
                       const float* W_init_c, const float* b_init_c,
                       float* c, f16* h_h, f16* h_all, unsigned* bar) {
    if (blockIdx.x == 64) {
        int t = threadIdx.x;
        for (int i = t; i < 512; i += 256) bar[i] = 0u;
        for (int i = t; i < 32 * 512; i += 256) h_all[(long)2016 * 512 + i] = (f16)0.0f;
        return;
    }
    __shared__ float ms[512];
    int b = blockIdx.x >> 1, which = blockIdx.x & 1;
    const float* W = which ? W_init_c : W_init_h;
    const float* bb = which ? b_init_c : b_init_h;
    int t = threadIdx.x;
    ms[t] = mean_enc[b * 512 + t];
    ms[t + 256] = mean_enc[b * 512 + t + 256];
    __syncthreads();
    for (int jj = 0; jj < 2; ++jj) {
        int j = t + jj * 256;
        float acc = bb[j];
        for (int k = 0; k < 512; ++k) acc += ms[k] * W[k * 512 + j];
        if (which) c[b * 512 + j] = acc;
        else h_h[b * 512 + j] = (f16)acc;
    }
}

// ---------------- enc_att = enc @ W_enc_att + b (fp16 MFMA) ----------------
__global__ __launch_bounds__(256, 2) void k_encatt(const f16* A, const f16* Bt,
                                                   const float* bias, f16* Cout) {
    __shared__ __align__(16) f16 As[128 * 32];
    __shared__ __align__(16) f16 Bs[128 * 32];
    int m0 = blockIdx.x * 128, n0 = blockIdx.y * 128;
    int t = threadIdx.x, w = t >> 6, lane = t & 63;
    int wm = (w >> 1) * 64, wn = (w & 1) * 64;
    int lm = lane & 15, lq = lane >> 4;
    f4v acc[4][4];
    for (int mi = 0; mi < 4; ++mi)
        for (int ni = 0; ni < 4; ++ni) acc[mi][ni] = (f4v){0.f, 0.f, 0.f, 0.f};
    for (int kb = 0; kb < 512; kb += 32) {
        for (int i = 0; i < 2; ++i) {
            int li = t + i * 256;
            int row = li >> 2, q = li & 3;
            *(uint4*)&As[row * 32 + q * 8] = *(const uint4*)&A[(long)(m0 + row) * 512 + kb + q * 8];
            *(uint4*)&Bs[row * 32 + q * 8] = *(const uint4*)&Bt[(long)(n0 + row) * 512 + kb + q * 8];
        }
        __syncthreads();
        h8 af[4], bf[4];
        for (int i = 0; i < 4; ++i) {
            af[i] = *(const h8*)&As[(wm + i * 16 + lm) * 32 + lq * 8];
            bf[i] = *(const h8*)&Bs[(wn + i * 16 + lm) * 32 + lq * 8];
        }
        for (int mi = 0; mi < 4; ++mi)
            for (int ni = 0; ni < 4; ++ni)
                acc[mi][ni] = __builtin_amdgcn_mfma_f32_16x16x32_f16(af[mi], bf[ni], acc[mi][ni], 0, 0, 0);
        __syncthreads();
    }
    for (int mi = 0; mi < 4; ++mi)
        for (int ni = 0; ni < 4; ++ni)
            for (int r = 0; r < 4; ++r) {
                int row = m0 + wm + mi * 16 + lq * 4 + r;
                int col = n0 + wn + ni * 16 + lm;
                Cout[(long)row * 512 + col] = (f16)(acc[mi][ni][r] + bias[col]);
            }
}

// ---------------- final FC: preds = h_all @ W_fc + b_fc (fp16 MFMA, masked) ----------------
__global__ __launch_bounds__(256, 2) void k_fc(const f16* A, const f16* Bt, const float* bias,
                                               const int* cl, float* out) {
    __shared__ __align__(16) f16 As[128 * 32];
    __shared__ __align__(16) f16 Bs[128 * 32];
    int m0 = blockIdx.x * 128, n0 = blockIdx.y * 128;
    int t = threadIdx.x, w = t >> 6, lane = t & 63;
    int wm = (w >> 1) * 64, wn = (w & 1) * 64;
    int lm = lane & 15, lq = lane >> 4;

    bool myact = false;
    if (t < 128) {
        int row = m0 + t;
        if (row < 2016) {
            int b = row / 63, tt = row - b * 63;
            myact = tt < (cl[b] - 1);
        }
    }
    int anyact = __syncthreads_or((int)myact);
    if (!anyact) {
        for (int i = 0; i < 64; ++i) {
            int idx = t + i * 256;
            int row = m0 + (idx >> 7), col = n0 + (idx & 127);
            if (row < 2016 && col < 10000) out[(long)row * 10000 + col] = 0.0f;
        }
        return;
    }

    f4v acc[4][4];
    for (int mi = 0; mi < 4; ++mi)
        for (int ni = 0; ni < 4; ++ni) acc[mi][ni] = (f4v){0.f, 0.f, 0.f, 0.f};
    for (int kb = 0; kb < 512; kb += 32) {
        for (int i = 0; i < 2; ++i) {
            int li = t + i * 256;
            int row = li >> 2, q = li & 3;
            *(uint4*)&As[row * 32 + q * 8] = *(const uint4*)&A[(long)(m0 + row) * 512 + kb + q * 8];
            *(uint4*)&Bs[row * 32 + q * 8] = *(const uint4*)&Bt[(long)(n0 + row) * 512 + kb + q * 8];
        }
        __syncthreads();
        h8 af[4], bf[4];
        for (int i = 0; i < 4; ++i) {
            af[i] = *(const h8*)&As[(wm + i * 16 + lm) * 32 + lq * 8];
            bf[i] = *(const h8*)&Bs[(wn + i * 16 + lm) * 32 + lq * 8];
        }
        for (int mi = 0; mi < 4; ++mi)
            for (int ni = 0; ni < 4; ++ni)
                acc[mi][ni] = __builtin_amdgcn_mfma_f32_16x16x32_f16(af[mi], bf[ni], acc[mi][ni], 0, 0, 0);
        __syncthreads();
    }
    for (int mi = 0; mi < 4; ++mi)
        for (int ni = 0; ni < 4; ++ni)
            for (int r = 0; r < 4; ++r) {
                int row = m0 + wm + mi * 16 + lq * 4 + r;
                int col = n0 + wn + ni * 16 + lm;
                if (row < 2016 && col < 10000) {
                    int b = row / 63, tt = row - b * 63;
                    bool act = tt < (cl[b] - 1);
                    out[(long)row * 10000 + col] = act ? (acc[mi][ni][r] + bias[col]) : 0.0f;
                }
            }
}

// ---------------- persistent recurrent loop (3 barriers/step, 512-thread blocks) ------
// 8 INDEPENDENT groups of 32 blocks; group g owns batches g*4..g*4+3; group-local
// gbar32 barriers; early exit at the group's max caption length.
// This round:
//  - P1 restored to the R1 shape (emb+h staged together, all 8 waves on the gate
//    GEMV, 16-kk df split) — prework regression reverted.
//  - Gate col-slab remapped so n1 == n3: gate partials stay in LDS (gp_loc),
//    gp_part global buffer removed.
//  - Attention partials reduced by atomicAdd in P2 (awe2/psum2 at coherence
//    point), zeroed in P1 (barrier-separated). P3's 64 KB pawe combine becomes
//    an 8 KB awe2 read.
__global__ __launch_bounds__(512, 1) void k_loop(
    const f16* Wdf8, const float* b_df,
    const f16* Wpart8, const f16* Wmid8, const float* b_cat,
    const f16* enc_att_h, const f16* enc_t,
    const float* W_full, const float* emb, const int* caps, const int* cl,
    float* c, f16* h_h, float* da_gp, float* awe2, float* psum2,
    f16* h_all, unsigned* bar) {
    __shared__ __align__(16) unsigned xcat[4 * 512];   // [emb|h] f16x2 (8 KB)
    __shared__ float gred[8 * 4 * 64];                 // gate K-eighth partials (8 KB)
    __shared__ float dfred[512];                       // df partials (4 per col) (2 KB)
    __shared__ float gp_loc[4 * 64];                   // P1 gate partials (block-local cols)
    __shared__ float das2[512];                        // P2 dec_a
    __shared__ float es[32];                           // P2 exp(scores)
    __shared__ float ps4[4];                           // P3 1/sum(exp)
    __shared__ __align__(16) unsigned xms[4 * 256];    // P3 gated awe f16x2 (4 KB)
    __shared__ float g3[8 * 4 * 64];                   // P3 K-eighth partials (8 KB)
    __shared__ float gsm[256];                         // P3 gate values
    __shared__ __align__(16) f16 ea_s[25 * 512];       // staged enc_att slice (25.6 KB)
    __shared__ __align__(16) f16 et_s[512 * 26];       // staged enc_t slice, transposed (26.6 KB)

    const int bid = blockIdx.x, t = threadIdx.x;
    const int lane = t & 63, w = t >> 6;
    const int local = bid & 31;
    unsigned* gflags = bar + (bid >> 5) * 32;          // per-group flag line (128 B)

    const int bg = bid >> 5, b0 = bg * 4;
    const int cg = bid & 31;            // P1/P3 colgroup (n1 == n3 mapping)
    const int jg = bid & 31;
    // P2: group-local mapping — batch within group, 8 p-groups per batch
    const int b2 = b0 + ((bid >> 3) & 3), pg = bid & 7;
    const int nr = (196 - pg * 25) < 25 ? (196 - pg * 25) : 25;

    // step-invariant preloads
    float4 wfa = *(const float4*)(W_full + lane * 8);
    float4 wfb = *(const float4*)(W_full + lane * 8 + 4);
    const int nc3 = ((t & 63) >> 4) * 512 + jg * 16 + (t & 15);  // combine col (t<256)
    float bc_g = 0.f, bdf = 0.f;
    if (t < 256) bc_g = b_cat[nc3];
    if (t < 128) bdf = b_df[cg * 32 + (t & 31)];
    const int myb = b0 + (t >> 3);
    const int mycl = (t < 32) ? cl[myb] : 0;
    const int jp = t & 7;
    const int j0 = jg * 16 + jp * 2;
    // GEMV wave/lane constants (gate cols chosen so they match P3's needs)
    const int n1 = (lane >> 4) * 512 + cg * 16 + (lane & 15);     // P1 gate col == n3
    const int n3 = n1;                                            // P3 gate col
    const int dfcol = cg * 32 + (lane & 31);                      // P1 df col
    const int ksub = lane >> 5, wb2 = w & 3, kh = w >> 2;         // P1 df split

    // group trip count (caption_lengths sorted desc; take max of 4 for safety)
    int steps_g;
    {
        int c0v = cl[b0], c1v = cl[b0 + 1], c2v = cl[b0 + 2], c3v = cl[b0 + 3];
        int m01 = c0v > c1v ? c0v : c1v;
        int m23 = c2v > c3v ? c2v : c3v;
        steps_g = (m01 > m23 ? m01 : m23) - 1;
    }

    // ---- stage step-invariant P2 slices into LDS (once) ----
    {
        int r = t >> 6, cv = t & 63;   // wave-uniform row, lane = 8-f16 chunk
        for (int base = 0; base < 25; base += 8) {
            int rr = base + r;
            if (rr < nr) {
                const long rowoff = ((long)b2 * 196 + pg * 25 + rr) * 512 + cv * 8;
                uint4 va = *(const uint4*)(enc_att_h + rowoff);
                *(uint4*)&ea_s[rr * 512 + cv * 8] = va;
                uint4 vt = *(const uint4*)(enc_t + rowoff);
                f16 tmp[8]; *(uint4*)tmp = vt;
#pragma unroll
                for (int e = 0; e < 8; ++e) et_s[(cv * 8 + e) * 26 + rr] = tmp[e];
            }
        }
    }

    for (int step = 0; step < steps_g; ++step) {
        // ================= P1 =================
        {
            // zero this step's attention accumulators (P2 atomics start after bar 1)
            if (t < 64) {
                int idx = local * 64 + t;          // 0..2047 across the group
                agent_st_f(awe2 + (long)(b0 + (idx >> 9)) * 512 + (idx & 511), 0.f);
            }
            if (local == 0 && t < 4) agent_st_f(psum2 + b0 + t, 0.f);
#pragma unroll
            for (int i = 0; i < 2; ++i) {
                int idx = t + i * 512;
                int b = idx >> 8, off = idx & 255;
                int tok = caps[(b0 + b) * 64 + step];
                float2 ev = *(const float2*)(emb + (long)tok * 512 + off * 2);
                h2 pe; pe.x = (f16)ev.x; pe.y = (f16)ev.y;
                xcat[b * 512 + off] = h22u(pe);
                xcat[b * 512 + 256 + off] = agent_ld_u((const unsigned*)h_h + (b0 + b) * 256 + off);
            }
            __syncthreads();
            // gate partials: wave w -> K-eighth (16 k8), 4 batches per lane
            {
                const f16* wp = Wpart8 + (long)n1 * 8;
                float a0 = 0.f, a1 = 0.f, a2 = 0.f, a3 = 0.f;
                for (int kk = 0; kk < 16; ++kk) {
                    int k8 = w * 16 + kk;
                    uint4 wv = *(const uint4*)(wp + (long)k8 * 16384);
                    uint4 x0 = *(const uint4*)&xcat[0 * 512 + k8 * 4];
                    uint4 x1 = *(const uint4*)&xcat[1 * 512 + k8 * 4];
                    uint4 x2 = *(const uint4*)&xcat[2 * 512 + k8 * 4];
                    uint4 x3 = *(const uint4*)&xcat[3 * 512 + k8 * 4];
                    a0 = fdot2(u2h2(x0.x), u2h2(wv.x), a0);
                    a0 = fdot2(u2h2(x0.y), u2h2(wv.y), a0);
                    a0 = fdot2(u2h2(x0.z), u2h2(wv.z), a0);
                    a0 = fdot2(u2h2(x0.w), u2h2(wv.w), a0);
                    a1 = fdot2(u2h2(x1.x), u2h2(wv.x), a1);
                    a1 = fdot2(u2h2(x1.y), u2h2(wv.y), a1);
                    a1 = fdot2(u2h2(x1.z), u2h2(wv.z), a1);
                    a1 = fdot2(u2h2(x1.w), u2h2(wv.w), a1);
                    a2 = fdot2(u2h2(x2.x), u2h2(wv.x), a2);
                    a2 = fdot2(u2h2(x2.y), u2h2(wv.y), a2);
                    a2 = fdot2(u2h2(x2.z), u2h2(wv.z), a2);
                    a2 = fdot2(u2h2(x2.w), u2h2(wv.w), a2);
                    a3 = fdot2(u2h2(x3.x), u2h2(wv.x), a3);
                    a3 = fdot2(u2h2(x3.y), u2h2(wv.y), a3);
                    a3 = fdot2(u2h2(x3.z), u2h2(wv.z), a3);
                    a3 = fdot2(u2h2(x3.w), u2h2(wv.w), a3);
                }
                gred[(w * 4 + 0) * 64 + lane] = a0;
                gred[(w * 4 + 1) * 64 + lane] = a1;
                gred[(w * 4 + 2) * 64 + lane] = a2;
                gred[(w * 4 + 3) * 64 + lane] = a3;
            }
            // dec/f_beta: wave -> (batch wb2, K-half kh); lane -> (col, K-quarter ksub)
            {
                const f16* wdf = Wdf8 + (long)dfcol * 8;
                const unsigned* hx = &xcat[wb2 * 512 + 256];
                int kbase = kh * 32 + ksub * 16;
                float a = 0.f;
                for (int kk = 0; kk < 16; ++kk) {
                    int k8 = kbase + kk;
                    uint4 wv = *(const uint4*)(wdf + (long)k8 * 8192);
                    uint4 xv = *(const uint4*)&hx[k8 * 4];
                    a = fdot2(u2h2(xv.x), u2h2(wv.x), a);
                    a = fdot2(u2h2(xv.y), u2h2(wv.y), a);
                    a = fdot2(u2h2(xv.z), u2h2(wv.z), a);
                    a = fdot2(u2h2(xv.w), u2h2(wv.w), a);
                }
                dfred[(wb2 * 32 + (lane & 31)) * 4 + kh * 2 + ksub] = a;
            }
            __syncthreads();
            if (t < 256) {
                int b = t >> 6, col = t & 63;
                float v = bc_g;
#pragma unroll
                for (int ww = 0; ww < 8; ++ww) v += gred[(ww * 4 + b) * 64 + col];
                gp_loc[b * 64 + col] = v;       // stays in LDS for this block's P3
            }
            if (t < 128) {
                int b = t >> 5, col = t & 31;
                const float* dr = &dfred[(b * 32 + col) * 4];
                float v = dr[0] + dr[1] + dr[2] + dr[3] + bdf;
                agent_st_f(da_gp + (long)(b0 + b) * 1024 + cg * 32 + col, v);
            }
        }
        gbar32(gflags, (unsigned)step * 3u + 1u, local);

        // ================= P2: scores + exp + atomic weighted sums (LDS-staged) ========
        {
            das2[t] = agent_ld_f(da_gp + (long)b2 * 1024 + t);
            __syncthreads();
            float4 dv0 = *(const float4*)&das2[lane * 8];
            float4 dv1 = *(const float4*)&das2[lane * 8 + 4];
#pragma unroll
            for (int i = 0; i < 4; ++i) {
                int r = w + i * 8;
                if (r < nr) {
                    uint4 ev = *(const uint4*)&ea_s[r * 512 + lane * 8];
                    h2 e0 = u2h2(ev.x), e1 = u2h2(ev.y), e2 = u2h2(ev.z), e3 = u2h2(ev.w);
                    float a = 0.f;
                    a += fmaxf((float)e0.x + dv0.x, 0.f) * wfa.x;
                    a += fmaxf((float)e0.y + dv0.y, 0.f) * wfa.y;
                    a += fmaxf((float)e1.x + dv0.z, 0.f) * wfa.z;
                    a += fmaxf((float)e1.y + dv0.w, 0.f) * wfa.w;
                    a += fmaxf((float)e2.x + dv1.x, 0.f) * wfb.x;
                    a += fmaxf((float)e2.y + dv1.y, 0.f) * wfb.y;
                    a += fmaxf((float)e3.x + dv1.z, 0.f) * wfb.z;
                    a += fmaxf((float)e3.y + dv1.w, 0.f) * wfb.w;
                    for (int m = 32; m; m >>= 1) a += __shfl_xor(a, m);
                    if (lane == 0) es[r] = expf(a);
                }
            }
            __syncthreads();
            {
                float acc = 0.f;
                for (int r = 0; r < nr; ++r) acc += es[r] * (float)et_s[t * 26 + r];
                agent_add_f(awe2 + (long)b2 * 512 + t, acc);
                if (t == 0) {
                    float s = 0.f;
                    for (int r = 0; r < nr; ++r) s += es[r];
                    agent_add_f(psum2 + b2, s);
                }
            }
        }
        gbar32(gflags, (unsigned)step * 3u + 2u, local);

        // ================= P3 =================
        {
            if (t < 4) ps4[t] = 1.0f / agent_ld_f(psum2 + b0 + t);
            __syncthreads();
#pragma unroll
            for (int i = 0; i < 2; ++i) {
                int idx = t + i * 512;             // 0..1023 = 4 b x 256 c-pairs
                int bb = idx >> 8, cp = idx & 255;
                float2 aw = u2f2(agent_ld_u64(
                    (const unsigned long long*)awe2 + (long)(b0 + bb) * 256 + cp));
                float inv = ps4[bb];
                float2 fb = u2f2(agent_ld_u64(
                    (const unsigned long long*)da_gp + (long)(b0 + bb) * 512 + 256 + cp));
                h2 pa;
                pa.x = (f16)(sigf(fb.x) * aw.x * inv);
                pa.y = (f16)(sigf(fb.y) * aw.y * inv);
                xms[bb * 256 + cp] = h22u(pa);
            }
            __syncthreads();
            // mid-GEMM: wave -> K-eighth (8 k8), 4 batches per lane
            {
                const f16* wp = Wmid8 + (long)n3 * 8;
                float a0 = 0.f, a1 = 0.f, a2 = 0.f, a3 = 0.f;
                for (int kk = 0; kk < 8; ++kk) {
                    int k8 = w * 8 + kk;
                    uint4 wv = *(const uint4*)(wp + (long)k8 * 16384);
                    uint4 x0 = *(const uint4*)&xms[0 * 256 + k8 * 4];
                    uint4 x1 = *(const uint4*)&xms[1 * 256 + k8 * 4];
                    uint4 x2 = *(const uint4*)&xms[2 * 256 + k8 * 4];
                    uint4 x3 = *(const uint4*)&xms[3 * 256 + k8 * 4];
                    a0 = fdot2(u2h2(x0.x), u2h2(wv.x), a0);
                    a0 = fdot2(u2h2(x0.y), u2h2(wv.y), a0);
                    a0 = fdot2(u2h2(x0.z), u2h2(wv.z), a0);
                    a0 = fdot2(u2h2(x0.w), u2h2(wv.w), a0);
                    a1 = fdot2(u2h2(x1.x), u2h2(wv.x), a1);
                    a1 = fdot2(u2h2(x1.y), u2h2(wv.y), a1);
                    a1 = fdot2(u2h2(x1.z), u2h2(wv.z), a1);
                    a1 = fdot2(u2h2(x1.w), u2h2(wv.w), a1);
                    a2 = fdot2(u2h2(x2.x), u2h2(wv.x), a2);
                    a2 = fdot2(u2h2(x2.y), u2h2(wv.y), a2);
                    a2 = fdot2(u2h2(x2.z), u2h2(wv.z), a2);
                    a2 = fdot2(u2h2(x2.w), u2h2(wv.w), a2);
                    a3 = fdot2(u2h2(x3.x), u2h2(wv.x), a3);
                    a3 = fdot2(u2h2(x3.y), u2h2(wv.y), a3);
                    a3 = fdot2(u2h2(x3.z), u2h2(wv.z), a3);
                    a3 = fdot2(u2h2(x3.w), u2h2(wv.w), a3);
                }
                g3[(w * 4 + 0) * 64 + lane] = a0;
                g3[(w * 4 + 1) * 64 + lane] = a1;
                g3[(w * 4 + 2) * 64 + lane] = a2;
                g3[(w * 4 + 3) * 64 + lane] = a3;
            }
            __syncthreads();
            if (t < 256) {
                int b = t >> 6, l2 = t & 63;
                float v = gp_loc[b * 64 + l2];
#pragma unroll
                for (int ww = 0; ww < 8; ++ww) v += g3[(ww * 4 + b) * 64 + l2];
                gsm[b * 64 + l2] = v;
            }
            __syncthreads();
            if (t < 32) {
                int bl = t >> 3;
                int l0 = jp * 2, l1 = jp * 2 + 1;
                float gi0 = gsm[bl * 64 + l0],      gi1 = gsm[bl * 64 + l1];
                float gf0 = gsm[bl * 64 + 16 + l0], gf1 = gsm[bl * 64 + 16 + l1];
                float gg0 = gsm[bl * 64 + 32 + l0], gg1 = gsm[bl * 64 + 32 + l1];
                float go0 = gsm[bl * 64 + 48 + l0], go1 = gsm[bl * 64 + 48 + l1];
                float2 cold = *(float2*)(c + (long)myb * 512 + j0);
                float cn0 = sigf(gf0) * cold.x + sigf(gi0) * tanhf(gg0);
                float hn0 = sigf(go0) * tanhf(cn0);
                float cn1 = sigf(gf1) * cold.y + sigf(gi1) * tanhf(gg1);
                float hn1 = sigf(go1) * tanhf(cn1);
                h2 oldh = u2h2(agent_ld_u((const unsigned*)h_h + myb * 256 + (j0 >> 1)));
                bool act = step < (mycl - 1);
                float hv0, hv1, cv0, cv1;
                if (act) { hv0 = hn0; hv1 = hn1; cv0 = cn0; cv1 = cn1; }
                else { hv0 = (float)oldh.x; hv1 = (float)oldh.y; cv0 = cold.x; cv1 = cold.y; }
                float2 cw; cw.x = cv0; cw.y = cv1;
                *(float2*)(c + (long)myb * 512 + j0) = cw;
                h2 hp; hp.x = (f16)hv0; hp.y = (f16)hv1;
                unsigned pv = h22u(hp);
                agent_st_u((unsigned*)h_h + myb * 256 + (j0 >> 1), pv);
                *((unsigned*)h_all + ((long)myb * 63 + step) * 256 + (j0 >> 1)) = pv;
            }
        }
        gbar32(gflags, (unsigned)step * 3u + 3u, local);
    }
}

// ---------------- launcher ----------------
extern "C" void kernel_launch(void* const* d_in, const int* in_sizes, int n_in,
                              void* d_out, int out_size, void* d_ws, size_t ws_size,
                              hipStream_t stream) {
    const float* encoder_out = (const float*)d_in[0];
    const int* caps = (const int*)d_in[1];
    const int* cl = (const int*)d_in[2];
    const float* emb = (const float*)d_in[3];
    const float* W_enc_att = (const float*)d_in[4];
    const float* b_enc_att = (const float*)d_in[5];
    const float* W_dec_att = (const float*)d_in[6];
    const float* b_dec_att = (const float*)d_in[7];
    const float* W_full_att = (const float*)d_in[8];
    const float* W_init_h = (const float*)d_in[10];
    const float* b_init_h = (const float*)d_in[11];
    const float* W_init_c = (const float*)d_in[12];
    const float* b_init_c = (const float*)d_in[13];
    const float* W_f_beta = (const float*)d_in[14];
    const float* b_f_beta = (const float*)d_in[15];
    const float* W_ih = (const float*)d_in[16];
    const float* b_ih = (const float*)d_in[17];
    const float* W_hh = (const float*)d_in[18];
    const float* b_hh = (const float*)d_in[19];
    const float* W_fc = (const float*)d_in[20];
    const float* b_fc = (const float*)d_in[21];

    char* p = (char*)d_ws;
    auto take = [&](size_t bytes) {
        char* r = p;
        p += (bytes + 255) & ~(size_t)255;
        return r;
    };
    f16* enc_t     = (f16*)take((size_t)32 * 196 * 512 * 2);
    f16* enc_att_h = (f16*)take((size_t)32 * 196 * 512 * 2);
    f16* W_encT    = (f16*)take((size_t)512 * 512 * 2);
    f16* W_fcT     = (f16*)take((size_t)10112 * 512 * 2);
    f16* Wdf8      = (f16*)take((size_t)512 * 1024 * 2);
    f16* Wpart8    = (f16*)take((size_t)1024 * 2048 * 2);
    f16* Wmid8     = (f16*)take((size_t)512 * 2048 * 2);
    f16* h_all     = (f16*)take((size_t)2048 * 512 * 2);
    f16* h_h       = (f16*)take((size_t)32 * 512 * 2);
    float* b_df    = (float*)take(1024 * 4);
    float* b_cat   = (float*)take(2048 * 4);
    float* mean_e  = (float*)take((size_t)32 * 512 * 4);
    float* c_st    = (float*)take((size_t)32 * 512 * 4);
    float* da_gp   = (float*)take((size_t)32 * 1024 * 4);
    float* awe2    = (float*)take((size_t)32 * 512 * 4);
    float* psum2   = (float*)take((size_t)32 * 4);
    unsigned* bar  = (unsigned*)take(2048);

    k_prep_w<<<1024, 256, 0, stream>>>(W_enc_att, W_dec_att, W_f_beta,
                                       b_dec_att, b_f_beta, b_ih, b_hh,
                                       W_encT, Wdf8, b_df, b_cat);
    k_tr_fc<<<dim3(158, 8), 256, 0, stream>>>(W_fc, W_fcT);
    k_pack_part<<<dim3(16, 32), 256, 0, stream>>>(W_ih, W_hh, Wpart8);
    k_pack_mid<<<dim3(8, 32), 256, 0, stream>>>(W_ih, Wmid8);
    k_prep_enc<<<256, 256, 0, stream>>>(encoder_out, enc_t, mean_e);
    k_h0c0<<<65, 256, 0, stream>>>(mean_e, W_init_h, b_init_h, W_init_c, b_init_c,
                                   c_st, h_h, h_all, bar);
    k_encatt<<<dim3(49, 4), 256, 0, stream>>>(enc_t, W_encT, b_enc_att, enc_att_h);
    k_loop<<<256, 512, 0, stream>>>(Wdf8, b_df, Wpart8, Wmid8, b_cat,
                                    enc_att_h, enc_t, W_full_att, emb, caps, cl,
                                    c_st, h_h, da_gp, awe2, psum2, h_all, bar);
    k_fc<<<dim3(16, 79), 256, 0, stream>>>(h_all, W_fcT, b_fc, cl, (float*)d_out);
}

// Round 7
// 1564.396 us; speedup vs baseline: 1.2239x; 1.0332x over previous
//
#include <hip/hip_runtime.h>
#include <cstdint>
#include <cstddef>

// ---------------- problem constants ----------------
// B=32, ENC=512, P=196 (14x14), ATT=512, EMB=512, DEC=512, VOCAB=10000, T=63
typedef _Float16 f16;
typedef _Float16 h2 __attribute__((ext_vector_type(2)));
typedef _Float16 h8 __attribute__((ext_vector_type(8)));
typedef float f4v __attribute__((ext_vector_type(4)));

// ---------------- helpers ----------------
__device__ __forceinline__ h2 u2h2(unsigned u) { return __builtin_bit_cast(h2, u); }
__device__ __forceinline__ unsigned h22u(h2 v) { return __builtin_bit_cast(unsigned, v); }
__device__ __forceinline__ float2 u2f2(unsigned long long u) { return __builtin_bit_cast(float2, u); }

__device__ __forceinline__ float agent_ld_f(const float* p) {
    return __hip_atomic_load(p, __ATOMIC_RELAXED, __HIP_MEMORY_SCOPE_AGENT);
}
__device__ __forceinline__ void agent_st_f(float* p, float v) {
    __hip_atomic_store(p, v, __ATOMIC_RELAXED, __HIP_MEMORY_SCOPE_AGENT);
}
__device__ __forceinline__ void agent_add_f(float* p, float v) {
    __hip_atomic_fetch_add(p, v, __ATOMIC_RELAXED, __HIP_MEMORY_SCOPE_AGENT);
}
__device__ __forceinline__ unsigned agent_ld_u(const unsigned* p) {
    return __hip_atomic_load(p, __ATOMIC_RELAXED, __HIP_MEMORY_SCOPE_AGENT);
}
__device__ __forceinline__ void agent_st_u(unsigned* p, unsigned v) {
    __hip_atomic_store(p, v, __ATOMIC_RELAXED, __HIP_MEMORY_SCOPE_AGENT);
}
__device__ __forceinline__ unsigned long long agent_ld_u64(const unsigned long long* p) {
    return __hip_atomic_load(p, __ATOMIC_RELAXED, __HIP_MEMORY_SCOPE_AGENT);
}

__device__ __forceinline__ float fdot2(h2 a, h2 b, float c) {
#if __has_builtin(__builtin_amdgcn_fdot2)
    return __builtin_amdgcn_fdot2(a, b, c, false);
#else
    return c + (float)a.x * (float)b.x + (float)a.y * (float)b.y;
#endif
}
__device__ __forceinline__ float sigf(float x) { return 1.0f / (1.0f + expf(-x)); }

// per-group (32-block) all-to-all barrier. ALL-RELAXED atomics + compiler-only
// ordering (RELEASE/ACQUIRE would emit buffer_wbl2/buffer_inv and wipe L2
// weight residency). '>=' makes epoch-skew safe.
__device__ __forceinline__ void gbar32(unsigned* gflags, unsigned epoch, int local) {
    __syncthreads();
    if (threadIdx.x < 64) {
        if (threadIdx.x == 0) {
            asm volatile("s_waitcnt vmcnt(0)" ::: "memory");
            __hip_atomic_store(&gflags[local], epoch, __ATOMIC_RELAXED, __HIP_MEMORY_SCOPE_AGENT);
        }
        const int l = threadIdx.x & 31;
        bool ok;
        do {
            ok = (__hip_atomic_load(&gflags[l], __ATOMIC_RELAXED,
                                    __HIP_MEMORY_SCOPE_AGENT) >= epoch);
            if (!ok) __builtin_amdgcn_s_sleep(1);
        } while (__ballot(ok) != ~0ull);
        asm volatile("" ::: "memory");
    }
    __syncthreads();
}

// ---------------- prep: small weights / biases ----------------
__global__ void k_prep_w(const float* W_enc, const float* W_dec, const float* W_fb,
                         const float* b_dec, const float* b_fb,
                         const float* b_ih, const float* b_hh,
                         f16* W_encT, f16* Wdf8, float* b_df, float* b_cat) {
    const int S0 = 512 * 512;
    const int S2 = 512 * 1024;
    const int total = S0 + S2 + 1024 + 2048;
    for (int idx = blockIdx.x * 256 + threadIdx.x; idx < total; idx += gridDim.x * 256) {
        int i = idx;
        if (i < S0) { int n = i >> 9, k = i & 511; W_encT[i] = (f16)W_enc[k * 512 + n]; continue; }
        i -= S0;
        if (i < S2) {
            int k8 = i / 8192, r = i % 8192, col = r >> 3, kr = r & 7;
            int k = k8 * 8 + kr;
            float v = (col < 512) ? W_dec[k * 512 + col] : W_fb[k * 512 + (col - 512)];
            Wdf8[i] = (f16)v;
            continue;
        }
        i -= S2;
        if (i < 1024) { b_df[i] = (i < 512) ? b_dec[i] : b_fb[i - 512]; continue; }
        i -= 1024;
        b_cat[i] = b_ih[i] + b_hh[i];
    }
}

// ---------------- prep: tiled transpose W_fc -> W_fcT[n][k] fp16 ----------------
__global__ void k_tr_fc(const float* W_fc, f16* W_fcT) {
    __shared__ float tile[64][65];
    int n0 = blockIdx.x * 64;
    int k0 = blockIdx.y * 64;
    int t = threadIdx.x;
#pragma unroll
    for (int i = 0; i < 16; ++i) {
        int lin = t + i * 256;
        int kl = lin >> 6, nl = lin & 63;
        int n = n0 + nl;
        tile[kl][nl] = (n < 10000) ? W_fc[(long)(k0 + kl) * 10000 + n] : 0.0f;
    }
    __syncthreads();
#pragma unroll
    for (int i = 0; i < 2; ++i) {
        int lin = t + i * 256;
        int r = lin >> 3, cv = lin & 7;
        f16 v[8];
#pragma unroll
        for (int kr = 0; kr < 8; ++kr) v[kr] = (f16)tile[cv * 8 + kr][r];
        *(uint4*)&W_fcT[(long)(n0 + r) * 512 + k0 + cv * 8] = *(uint4*)v;
    }
}

// ---------------- prep: k8-repack [W_ih(top 512); W_hh] -> Wpart8 (K=1024) ----
__global__ void k_pack_part(const float* W_ih, const float* W_hh, f16* Wpart8) {
    __shared__ float tile[64][65];
    int k0 = blockIdx.x * 64;
    int n0 = blockIdx.y * 64;
    int t = threadIdx.x;
#pragma unroll
    for (int i = 0; i < 16; ++i) {
        int lin = t + i * 256;
        int kl = lin >> 6, nl = lin & 63;
        int k = k0 + kl;
        float v = (k < 512) ? W_ih[(long)k * 2048 + n0 + nl]
                            : W_hh[(long)(k - 512) * 2048 + n0 + nl];
        tile[kl][nl] = v;
    }
    __syncthreads();
#pragma unroll
    for (int i = 0; i < 2; ++i) {
        int lin = t + i * 256;
        int nl = lin & 63, k8l = lin >> 6;
        f16 v[8];
#pragma unroll
        for (int kr = 0; kr < 8; ++kr) v[kr] = (f16)tile[k8l * 8 + kr][nl];
        *(uint4*)&Wpart8[(long)(k0 / 8 + k8l) * 16384 + (long)(n0 + nl) * 8] = *(uint4*)v;
    }
}

// ---------------- prep: k8-repack W_ih(mid rows 512..1023) -> Wmid8 (K=512) ----------
__global__ void k_pack_mid(const float* W_ih, f16* Wmid8) {
    __shared__ float tile[64][65];
    int k0 = blockIdx.x * 64;
    int n0 = blockIdx.y * 64;
    int t = threadIdx.x;
#pragma unroll
    for (int i = 0; i < 16; ++i) {
        int lin = t + i * 256;
        int kl = lin >> 6, nl = lin & 63;
        tile[kl][nl] = W_ih[(long)(512 + k0 + kl) * 2048 + n0 + nl];
    }
    __syncthreads();
#pragma unroll
    for (int i = 0; i < 2; ++i) {
        int lin = t + i * 256;
        int nl = lin & 63, k8l = lin >> 6;
        f16 v[8];
#pragma unroll
        for (int kr = 0; kr < 8; ++kr) v[kr] = (f16)tile[k8l * 8 + kr][nl];
        *(uint4*)&Wmid8[(long)(k0 / 8 + k8l) * 16384 + (long)(n0 + nl) * 8] = *(uint4*)v;
    }
}

// ---------------- prep: enc transpose + mean ----------------
__global__ void k_prep_enc(const float* enc_out, f16* enc_t, float* mean_enc) {
    __shared__ float tile[64][197];
    int b = blockIdx.x >> 3, cc = blockIdx.x & 7, c0 = cc * 64;
    int t = threadIdx.x;
    const float* src = enc_out + ((long)b * 512 + c0) * 196;
    for (int i = 0; i < 49; ++i) {
        int lin = t + i * 256;
        int cl = lin / 196, p = lin % 196;
        tile[cl][p] = src[cl * 196 + p];
    }
    __syncthreads();
    if (t < 64) {
        float s = 0.f;
        for (int p = 0; p < 196; ++p) s += tile[t][p];
        mean_enc[b * 512 + c0 + t] = s * (1.0f / 196.0f);
    }
    __syncthreads();
    int cl = t & 63, pg = t >> 6;
    for (int i = 0; i < 49; ++i) {
        int p = pg * 49 + i;
        enc_t[((long)(b * 196 + p)) * 512 + c0 + cl] = (f16)tile[cl][p];
    }
}

// ---------------- h0/c0 + barrier/tail init ----------------
__global__ void k_h0c0(const float* mean_enc, const float* W_init_h, const float* b_init_h,
                       const float* W_init_c, const float* b_init_c,
                       float* c, f16* h_h, f16* h_all, unsigned* bar) {
    if (blockIdx.x == 64) {
        int t = threadIdx.x;
        for (int i = t; i < 512; i += 256) bar[i] = 0u;
        for (int i = t; i < 32 * 512; i += 256) h_all[(long)2016 * 512 + i] = (f16)0.0f;
        return;
    }
    __shared__ float ms[512];
    int b = blockIdx.x >> 1, which = blockIdx.x & 1;
    const float* W = which ? W_init_c : W_init_h;
    const float* bb = which ? b_init_c : b_init_h;
    int t = threadIdx.x;
    ms[t] = mean_enc[b * 512 + t];
    ms[t + 256] = mean_enc[b * 512 + t + 256];
    __syncthreads();
    for (int jj = 0; jj < 2; ++jj) {
        int j = t + jj * 256;
        float acc = bb[j];
        for (int k = 0; k < 512; ++k) acc += ms[k] * W[k * 512 + j];
        if (which) c[b * 512 + j] = acc;
        else h_h[b * 512 + j] = (f16)acc;
    }
}

// ---------------- enc_att = enc @ W_enc_att + b (fp16 MFMA) ----------------
__global__ __launch_bounds__(256, 2) void k_encatt(const f16* A, const f16* Bt,
                                                   const float* bias, f16* Cout) {
    __shared__ __align__(16) f16 As[128 * 32];
    __shared__ __align__(16) f16 Bs[128 * 32];
    int m0 = blockIdx.x * 128, n0 = blockIdx.y * 128;
    int t = threadIdx.x, w = t >> 6, lane = t & 63;
    int wm = (w >> 1) * 64, wn = (w & 1) * 64;
    int lm = lane & 15, lq = lane >> 4;
    f4v acc[4][4];
    for (int mi = 0; mi < 4; ++mi)
        for (int ni = 0; ni < 4; ++ni) acc[mi][ni] = (f4v){0.f, 0.f, 0.f, 0.f};
    for (int kb = 0; kb < 512; kb += 32) {
        for (int i = 0; i < 2; ++i) {
            int li = t + i * 256;
            int row = li >> 2, q = li & 3;
            *(uint4*)&As[row * 32 + q * 8] = *(const uint4*)&A[(long)(m0 + row) * 512 + kb + q * 8];
            *(uint4*)&Bs[row * 32 + q * 8] = *(const uint4*)&Bt[(long)(n0 + row) * 512 + kb + q * 8];
        }
        __syncthreads();
        h8 af[4], bf[4];
        for (int i = 0; i < 4; ++i) {
            af[i] = *(const h8*)&As[(wm + i * 16 + lm) * 32 + lq * 8];
            bf[i] = *(const h8*)&Bs[(wn + i * 16 + lm) * 32 + lq * 8];
        }
        for (int mi = 0; mi < 4; ++mi)
            for (int ni = 0; ni < 4; ++ni)
                acc[mi][ni] = __builtin_amdgcn_mfma_f32_16x16x32_f16(af[mi], bf[ni], acc[mi][ni], 0, 0, 0);
        __syncthreads();
    }
    for (int mi = 0; mi < 4; ++mi)
        for (int ni = 0; ni < 4; ++ni)
            for (int r = 0; r < 4; ++r) {
                int row = m0 + wm + mi * 16 + lq * 4 + r;
                int col = n0 + wn + ni * 16 + lm;
                Cout[(long)row * 512 + col] = (f16)(acc[mi][ni][r] + bias[col]);
            }
}

// ---------------- final FC: preds = h_all @ W_fc + b_fc (fp16 MFMA, masked) ----------------
__global__ __launch_bounds__(256, 2) void k_fc(const f16* A, const f16* Bt, const float* bias,
                                               const int* cl, float* out) {
    __shared__ __align__(16) f16 As[128 * 32];
    __shared__ __align__(16) f16 Bs[128 * 32];
    int m0 = blockIdx.x * 128, n0 = blockIdx.y * 128;
    int t = threadIdx.x, w = t >> 6, lane = t & 63;
    int wm = (w >> 1) * 64, wn = (w & 1) * 64;
    int lm = lane & 15, lq = lane >> 4;

    bool myact = false;
    if (t < 128) {
        int row = m0 + t;
        if (row < 2016) {
            int b = row / 63, tt = row - b * 63;
            myact = tt < (cl[b] - 1);
        }
    }
    int anyact = __syncthreads_or((int)myact);
    if (!anyact) {
        for (int i = 0; i < 64; ++i) {
            int idx = t + i * 256;
            int row = m0 + (idx >> 7), col = n0 + (idx & 127);
            if (row < 2016 && col < 10000) out[(long)row * 10000 + col] = 0.0f;
        }
        return;
    }

    f4v acc[4][4];
    for (int mi = 0; mi < 4; ++mi)
        for (int ni = 0; ni < 4; ++ni) acc[mi][ni] = (f4v){0.f, 0.f, 0.f, 0.f};
    for (int kb = 0; kb < 512; kb += 32) {
        for (int i = 0; i < 2; ++i) {
            int li = t + i * 256;
            int row = li >> 2, q = li & 3;
            *(uint4*)&As[row * 32 + q * 8] = *(const uint4*)&A[(long)(m0 + row) * 512 + kb + q * 8];
            *(uint4*)&Bs[row * 32 + q * 8] = *(const uint4*)&Bt[(long)(n0 + row) * 512 + kb + q * 8];
        }
        __syncthreads();
        h8 af[4], bf[4];
        for (int i = 0; i < 4; ++i) {
            af[i] = *(const h8*)&As[(wm + i * 16 + lm) * 32 + lq * 8];
            bf[i] = *(const h8*)&Bs[(wn + i * 16 + lm) * 32 + lq * 8];
        }
        for (int mi = 0; mi < 4; ++mi)
            for (int ni = 0; ni < 4; ++ni)
                acc[mi][ni] = __builtin_amdgcn_mfma_f32_16x16x32_f16(af[mi], bf[ni], acc[mi][ni], 0, 0, 0);
        __syncthreads();
    }
    for (int mi = 0; mi < 4; ++mi)
        for (int ni = 0; ni < 4; ++ni)
            for (int r = 0; r < 4; ++r) {
                int row = m0 + wm + mi * 16 + lq * 4 + r;
                int col = n0 + wn + ni * 16 + lm;
                if (row < 2016 && col < 10000) {
                    int b = row / 63, tt = row - b * 63;
                    bool act = tt < (cl[b] - 1);
                    out[(long)row * 10000 + col] = act ? (acc[mi][ni][r] + bias[col]) : 0.0f;
                }
            }
}

// ---------------- persistent recurrent loop (3 barriers/step, 512-thread blocks) ------
// EXACT R3 cross-block protocol (proven passing). This round's block-local changes:
//  - Wmid8 slice (this block's 64 n3-cols, 64 KB) staged to LDS once; P3 mid-GEMM
//    reads pure-LDS. Cuts per-step L2 weight streaming 7->5 MB/XCD.
//  - emb gather for step+1 moved into P3 (h-independent; writes xcat emb-half,
//    whose last reader was P1's GEMV two barriers earlier). P1 stages only h.
__global__ __launch_bounds__(512, 1) void k_loop(
    const f16* Wdf8, const float* b_df,
    const f16* Wpart8, const f16* Wmid8, const float* b_cat,
    const f16* enc_att_h, const f16* enc_t,
    const float* W_full, const float* emb, const int* caps, const int* cl,
    float* c, f16* h_h, float* da_gp, float* awe2, float* psum2,
    f16* h_all, unsigned* bar) {
    __shared__ __align__(16) unsigned xcat[4 * 512];   // [emb|h] f16x2 (8 KB)
    __shared__ float gred[8 * 4 * 64];                 // gate K-eighth partials (8 KB)
    __shared__ float dfred[512];                       // df partials (4 per col) (2 KB)
    __shared__ float gp_loc[4 * 64];                   // P1 gate partials (block-local cols)
    __shared__ float das2[512];                        // P2 dec_a
    __shared__ float es[32];                           // P2 exp(scores)
    __shared__ float ps4[4];                           // P3 1/sum(exp)
    __shared__ __align__(16) unsigned xms[4 * 256];    // P3 gated awe f16x2 (4 KB)
    __shared__ float g3[8 * 4 * 64];                   // P3 K-eighth partials (8 KB)
    __shared__ float gsm[256];                         // P3 gate values
    __shared__ __align__(16) f16 ea_s[25 * 512];       // staged enc_att slice (25.6 KB)
    __shared__ __align__(16) f16 et_s[512 * 26];       // staged enc_t slice, transposed (26.6 KB)
    __shared__ __align__(16) f16 mid_s[64 * 512];      // staged Wmid8 block cols (64 KB)

    const int bid = blockIdx.x, t = threadIdx.x;
    const int lane = t & 63, w = t >> 6;
    const int local = bid & 31;
    unsigned* gflags = bar + (bid >> 5) * 32;          // per-group flag line (128 B)

    const int bg = bid >> 5, b0 = bg * 4;
    const int cg = bid & 31;            // P1/P3 colgroup (n1 == n3 mapping)
    const int jg = bid & 31;
    // P2: group-local mapping — batch within group, 8 p-groups per batch
    const int b2 = b0 + ((bid >> 3) & 3), pg = bid & 7;
    const int nr = (196 - pg * 25) < 25 ? (196 - pg * 25) : 25;

    // step-invariant preloads
    float4 wfa = *(const float4*)(W_full + lane * 8);
    float4 wfb = *(const float4*)(W_full + lane * 8 + 4);
    const int nc3 = ((t & 63) >> 4) * 512 + jg * 16 + (t & 15);  // combine col (t<256)
    float bc_g = 0.f, bdf = 0.f;
    if (t < 256) bc_g = b_cat[nc3];
    if (t < 128) bdf = b_df[cg * 32 + (t & 31)];
    const int myb = b0 + (t >> 3);
    const int mycl = (t < 32) ? cl[myb] : 0;
    const int jp = t & 7;
    const int j0 = jg * 16 + jp * 2;
    // GEMV wave/lane constants (gate cols chosen so they match P3's needs)
    const int n1 = (lane >> 4) * 512 + cg * 16 + (lane & 15);     // P1 gate col == n3
    const int dfcol = cg * 32 + (lane & 31);                      // P1 df col
    const int ksub = lane >> 5, wb2 = w & 3, kh = w >> 2;         // P1 df split
    const int ci_l = (lane >> 4) * 16 + (lane & 15);              // P3 mid LDS col idx

    // group trip count (caption_lengths sorted desc; take max of 4 for safety)
    int steps_g;
    {
        int c0v = cl[b0], c1v = cl[b0 + 1], c2v = cl[b0 + 2], c3v = cl[b0 + 3];
        int m01 = c0v > c1v ? c0v : c1v;
        int m23 = c2v > c3v ? c2v : c3v;
        steps_g = (m01 > m23 ? m01 : m23) - 1;
    }

    // ---- stage step-invariant P2 slices + mid-weight slice into LDS (once) ----
    {
        int r = t >> 6, cv = t & 63;   // wave-uniform row, lane = 8-f16 chunk
        for (int base = 0; base < 25; base += 8) {
            int rr = base + r;
            if (rr < nr) {
                const long rowoff = ((long)b2 * 196 + pg * 25 + rr) * 512 + cv * 8;
                uint4 va = *(const uint4*)(enc_att_h + rowoff);
                *(uint4*)&ea_s[rr * 512 + cv * 8] = va;
                uint4 vt = *(const uint4*)(enc_t + rowoff);
                f16 tmp[8]; *(uint4*)tmp = vt;
#pragma unroll
                for (int e = 0; e < 8; ++e) et_s[(cv * 8 + e) * 26 + rr] = tmp[e];
            }
        }
        // mid-weight slice: 64 k8 x 64 cols (block's n3 set) x 8 f16 = 64 KB
#pragma unroll
        for (int i = 0; i < 8; ++i) {
            int u = t + i * 512;           // 0..4095 uint4s
            int k8 = u >> 6, ci = u & 63;
            int n = (ci >> 4) * 512 + jg * 16 + (ci & 15);
            *(uint4*)&mid_s[k8 * 512 + ci * 8] =
                *(const uint4*)(Wmid8 + (long)k8 * 16384 + (long)n * 8);
        }
        // emb gather for step 0 (ordered before P1 reads by P1's __syncthreads)
#pragma unroll
        for (int i = 0; i < 2; ++i) {
            int idx = t + i * 512;
            int b = idx >> 8, off = idx & 255;
            int tok = caps[(b0 + b) * 64 + 0];
            float2 ev = *(const float2*)(emb + (long)tok * 512 + off * 2);
            h2 pe; pe.x = (f16)ev.x; pe.y = (f16)ev.y;
            xcat[b * 512 + off] = h22u(pe);
        }
    }

    for (int step = 0; step < steps_g; ++step) {
        // ================= P1 =================
        {
            // zero this step's attention accumulators (P2 atomics start after bar 1)
            if (t < 64) {
                int idx = local * 64 + t;          // 0..2047 across the group
                agent_st_f(awe2 + (long)(b0 + (idx >> 9)) * 512 + (idx & 511), 0.f);
            }
            if (local == 0 && t < 4) agent_st_f(psum2 + b0 + t, 0.f);
            // stage h (emb half already written in previous P3 / pre-loop)
#pragma unroll
            for (int i = 0; i < 2; ++i) {
                int idx = t + i * 512;
                int b = idx >> 8, off = idx & 255;
                xcat[b * 512 + 256 + off] = agent_ld_u((const unsigned*)h_h + (b0 + b) * 256 + off);
            }
            __syncthreads();
            // gate partials: wave w -> K-eighth (16 k8), 4 batches per lane
            {
                const f16* wp = Wpart8 + (long)n1 * 8;
                float a0 = 0.f, a1 = 0.f, a2 = 0.f, a3 = 0.f;
                for (int kk = 0; kk < 16; ++kk) {
                    int k8 = w * 16 + kk;
                    uint4 wv = *(const uint4*)(wp + (long)k8 * 16384);
                    uint4 x0 = *(const uint4*)&xcat[0 * 512 + k8 * 4];
                    uint4 x1 = *(const uint4*)&xcat[1 * 512 + k8 * 4];
                    uint4 x2 = *(const uint4*)&xcat[2 * 512 + k8 * 4];
                    uint4 x3 = *(const uint4*)&xcat[3 * 512 + k8 * 4];
                    a0 = fdot2(u2h2(x0.x), u2h2(wv.x), a0);
                    a0 = fdot2(u2h2(x0.y), u2h2(wv.y), a0);
                    a0 = fdot2(u2h2(x0.z), u2h2(wv.z), a0);
                    a0 = fdot2(u2h2(x0.w), u2h2(wv.w), a0);
                    a1 = fdot2(u2h2(x1.x), u2h2(wv.x), a1);
                    a1 = fdot2(u2h2(x1.y), u2h2(wv.y), a1);
                    a1 = fdot2(u2h2(x1.z), u2h2(wv.z), a1);
                    a1 = fdot2(u2h2(x1.w), u2h2(wv.w), a1);
                    a2 = fdot2(u2h2(x2.x), u2h2(wv.x), a2);
                    a2 = fdot2(u2h2(x2.y), u2h2(wv.y), a2);
                    a2 = fdot2(u2h2(x2.z), u2h2(wv.z), a2);
                    a2 = fdot2(u2h2(x2.w), u2h2(wv.w), a2);
                    a3 = fdot2(u2h2(x3.x), u2h2(wv.x), a3);
                    a3 = fdot2(u2h2(x3.y), u2h2(wv.y), a3);
                    a3 = fdot2(u2h2(x3.z), u2h2(wv.z), a3);
                    a3 = fdot2(u2h2(x3.w), u2h2(wv.w), a3);
                }
                gred[(w * 4 + 0) * 64 + lane] = a0;
                gred[(w * 4 + 1) * 64 + lane] = a1;
                gred[(w * 4 + 2) * 64 + lane] = a2;
                gred[(w * 4 + 3) * 64 + lane] = a3;
            }
            // dec/f_beta: wave -> (batch wb2, K-half kh); lane -> (col, K-quarter ksub)
            {
                const f16* wdf = Wdf8 + (long)dfcol * 8;
                const unsigned* hx = &xcat[wb2 * 512 + 256];
                int kbase = kh * 32 + ksub * 16;
                float a = 0.f;
                for (int kk = 0; kk < 16; ++kk) {
                    int k8 = kbase + kk;
                    uint4 wv = *(const uint4*)(wdf + (long)k8 * 8192);
                    uint4 xv = *(const uint4*)&hx[k8 * 4];
                    a = fdot2(u2h2(xv.x), u2h2(wv.x), a);
                    a = fdot2(u2h2(xv.y), u2h2(wv.y), a);
                    a = fdot2(u2h2(xv.z), u2h2(wv.z), a);
                    a = fdot2(u2h2(xv.w), u2h2(wv.w), a);
                }
                dfred[(wb2 * 32 + (lane & 31)) * 4 + kh * 2 + ksub] = a;
            }
            __syncthreads();
            if (t < 256) {
                int b = t >> 6, col = t & 63;
                float v = bc_g;
#pragma unroll
                for (int ww = 0; ww < 8; ++ww) v += gred[(ww * 4 + b) * 64 + col];
                gp_loc[b * 64 + col] = v;       // stays in LDS for this block's P3
            }
            if (t < 128) {
                int b = t >> 5, col = t & 31;
                const float* dr = &dfred[(b * 32 + col) * 4];
                float v = dr[0] + dr[1] + dr[2] + dr[3] + bdf;
                agent_st_f(da_gp + (long)(b0 + b) * 1024 + cg * 32 + col, v);
            }
        }
        gbar32(gflags, (unsigned)step * 3u + 1u, local);

        // ================= P2: scores + exp + atomic weighted sums (LDS-staged) ========
        {
            das2[t] = agent_ld_f(da_gp + (long)b2 * 1024 + t);
            __syncthreads();
            float4 dv0 = *(const float4*)&das2[lane * 8];
            float4 dv1 = *(const float4*)&das2[lane * 8 + 4];
#pragma unroll
            for (int i = 0; i < 4; ++i) {
                int r = w + i * 8;
                if (r < nr) {
                    uint4 ev = *(const uint4*)&ea_s[r * 512 + lane * 8];
                    h2 e0 = u2h2(ev.x), e1 = u2h2(ev.y), e2 = u2h2(ev.z), e3 = u2h2(ev.w);
                    float a = 0.f;
                    a += fmaxf((float)e0.x + dv0.x, 0.f) * wfa.x;
                    a += fmaxf((float)e0.y + dv0.y, 0.f) * wfa.y;
                    a += fmaxf((float)e1.x + dv0.z, 0.f) * wfa.z;
                    a += fmaxf((float)e1.y + dv0.w, 0.f) * wfa.w;
                    a += fmaxf((float)e2.x + dv1.x, 0.f) * wfb.x;
                    a += fmaxf((float)e2.y + dv1.y, 0.f) * wfb.y;
                    a += fmaxf((float)e3.x + dv1.z, 0.f) * wfb.z;
                    a += fmaxf((float)e3.y + dv1.w, 0.f) * wfb.w;
                    for (int m = 32; m; m >>= 1) a += __shfl_xor(a, m);
                    if (lane == 0) es[r] = expf(a);
                }
            }
            __syncthreads();
            {
                float acc = 0.f;
                for (int r = 0; r < nr; ++r) acc += es[r] * (float)et_s[t * 26 + r];
                agent_add_f(awe2 + (long)b2 * 512 + t, acc);
                if (t == 0) {
                    float s = 0.f;
                    for (int r = 0; r < nr; ++r) s += es[r];
                    agent_add_f(psum2 + b2, s);
                }
            }
        }
        gbar32(gflags, (unsigned)step * 3u + 2u, local);

        // ================= P3 =================
        {
            if (t < 4) ps4[t] = 1.0f / agent_ld_f(psum2 + b0 + t);
            __syncthreads();
#pragma unroll
            for (int i = 0; i < 2; ++i) {
                int idx = t + i * 512;             // 0..1023 = 4 b x 256 c-pairs
                int bb = idx >> 8, cp = idx & 255;
                float2 aw = u2f2(agent_ld_u64(
                    (const unsigned long long*)awe2 + (long)(b0 + bb) * 256 + cp));
                float inv = ps4[bb];
                float2 fb = u2f2(agent_ld_u64(
                    (const unsigned long long*)da_gp + (long)(b0 + bb) * 512 + 256 + cp));
                h2 pa;
                pa.x = (f16)(sigf(fb.x) * aw.x * inv);
                pa.y = (f16)(sigf(fb.y) * aw.y * inv);
                xms[bb * 256 + cp] = h22u(pa);
            }
            __syncthreads();
            // emb pre-gather for step+1 (h-independent; xcat emb-half's last reader
            // was P1's GEMV, two barriers ago; next reader is P1(step+1) after bar3)
            {
#pragma unroll
                for (int i = 0; i < 2; ++i) {
                    int idx = t + i * 512;
                    int b = idx >> 8, off = idx & 255;
                    int tok = caps[(b0 + b) * 64 + step + 1];
                    float2 ev = *(const float2*)(emb + (long)tok * 512 + off * 2);
                    h2 pe; pe.x = (f16)ev.x; pe.y = (f16)ev.y;
                    xcat[b * 512 + off] = h22u(pe);
                }
            }
            // mid-GEMM (pure LDS): wave -> K-eighth (8 k8), 4 batches per lane
            {
                const f16* wp = mid_s + ci_l * 8;
                float a0 = 0.f, a1 = 0.f, a2 = 0.f, a3 = 0.f;
                for (int kk = 0; kk < 8; ++kk) {
                    int k8 = w * 8 + kk;
                    uint4 wv = *(const uint4*)(wp + k8 * 512);
                    uint4 x0 = *(const uint4*)&xms[0 * 256 + k8 * 4];
                    uint4 x1 = *(const uint4*)&xms[1 * 256 + k8 * 4];
                    uint4 x2 = *(const uint4*)&xms[2 * 256 + k8 * 4];
                    uint4 x3 = *(const uint4*)&xms[3 * 256 + k8 * 4];
                    a0 = fdot2(u2h2(x0.x), u2h2(wv.x), a0);
                    a0 = fdot2(u2h2(x0.y), u2h2(wv.y), a0);
                    a0 = fdot2(u2h2(x0.z), u2h2(wv.z), a0);
                    a0 = fdot2(u2h2(x0.w), u2h2(wv.w), a0);
                    a1 = fdot2(u2h2(x1.x), u2h2(wv.x), a1);
                    a1 = fdot2(u2h2(x1.y), u2h2(wv.y), a1);
                    a1 = fdot2(u2h2(x1.z), u2h2(wv.z), a1);
                    a1 = fdot2(u2h2(x1.w), u2h2(wv.w), a1);
                    a2 = fdot2(u2h2(x2.x), u2h2(wv.x), a2);
                    a2 = fdot2(u2h2(x2.y), u2h2(wv.y), a2);
                    a2 = fdot2(u2h2(x2.z), u2h2(wv.z), a2);
                    a2 = fdot2(u2h2(x2.w), u2h2(wv.w), a2);
                    a3 = fdot2(u2h2(x3.x), u2h2(wv.x), a3);
                    a3 = fdot2(u2h2(x3.y), u2h2(wv.y), a3);
                    a3 = fdot2(u2h2(x3.z), u2h2(wv.z), a3);
                    a3 = fdot2(u2h2(x3.w), u2h2(wv.w), a3);
                }
                g3[(w * 4 + 0) * 64 + lane] = a0;
                g3[(w * 4 + 1) * 64 + lane] = a1;
                g3[(w * 4 + 2) * 64 + lane] = a2;
                g3[(w * 4 + 3) * 64 + lane] = a3;
            }
            __syncthreads();
            if (t < 256) {
                int b = t >> 6, l2 = t & 63;
                float v = gp_loc[b * 64 + l2];
#pragma unroll
                for (int ww = 0; ww < 8; ++ww) v += g3[(ww * 4 + b) * 64 + l2];
                gsm[b * 64 + l2] = v;
            }
            __syncthreads();
            if (t < 32) {
                int bl = t >> 3;
                int l0 = jp * 2, l1 = jp * 2 + 1;
                float gi0 = gsm[bl * 64 + l0],      gi1 = gsm[bl * 64 + l1];
                float gf0 = gsm[bl * 64 + 16 + l0], gf1 = gsm[bl * 64 + 16 + l1];
                float gg0 = gsm[bl * 64 + 32 + l0], gg1 = gsm[bl * 64 + 32 + l1];
                float go0 = gsm[bl * 64 + 48 + l0], go1 = gsm[bl * 64 + 48 + l1];
                float2 cold = *(float2*)(c + (long)myb * 512 + j0);
                float cn0 = sigf(gf0) * cold.x + sigf(gi0) * tanhf(gg0);
                float hn0 = sigf(go0) * tanhf(cn0);
                float cn1 = sigf(gf1) * cold.y + sigf(gi1) * tanhf(gg1);
                float hn1 = sigf(go1) * tanhf(cn1);
                h2 oldh = u2h2(agent_ld_u((const unsigned*)h_h + myb * 256 + (j0 >> 1)));
                bool act = step < (mycl - 1);
                float hv0, hv1, cv0, cv1;
                if (act) { hv0 = hn0; hv1 = hn1; cv0 = cn0; cv1 = cn1; }
                else { hv0 = (float)oldh.x; hv1 = (float)oldh.y; cv0 = cold.x; cv1 = cold.y; }
                float2 cw; cw.x = cv0; cw.y = cv1;
                *(float2*)(c + (long)myb * 512 + j0) = cw;
                h2 hp; hp.x = (f16)hv0; hp.y = (f16)hv1;
                unsigned pv = h22u(hp);
                agent_st_u((unsigned*)h_h + myb * 256 + (j0 >> 1), pv);
                *((unsigned*)h_all + ((long)myb * 63 + step) * 256 + (j0 >> 1)) = pv;
            }
        }
        gbar32(gflags, (unsigned)step * 3u + 3u, local);
    }
}

// ---------------- launcher ----------------
extern "C" void kernel_launch(void* const* d_in, const int* in_sizes, int n_in,
                              void* d_out, int out_size, void* d_ws, size_t ws_size,
                              hipStream_t stream) {
    const float* encoder_out = (const float*)d_in[0];
    const int* caps = (const int*)d_in[1];
    const int* cl = (const int*)d_in[2];
    const float* emb = (const float*)d_in[3];
    const float* W_enc_att = (const float*)d_in[4];
    const float* b_enc_att = (const float*)d_in[5];
    const float* W_dec_att = (const float*)d_in[6];
    const float* b_dec_att = (const float*)d_in[7];
    const float* W_full_att = (const float*)d_in[8];
    const float* W_init_h = (const float*)d_in[10];
    const float* b_init_h = (const float*)d_in[11];
    const float* W_init_c = (const float*)d_in[12];
    const float* b_init_c = (const float*)d_in[13];
    const float* W_f_beta = (const float*)d_in[14];
    const float* b_f_beta = (const float*)d_in[15];
    const float* W_ih = (const float*)d_in[16];
    const float* b_ih = (const float*)d_in[17];
    const float* W_hh = (const float*)d_in[18];
    const float* b_hh = (const float*)d_in[19];
    const float* W_fc = (const float*)d_in[20];
    const float* b_fc = (const float*)d_in[21];

    char* p = (char*)d_ws;
    auto take = [&](size_t bytes) {
        char* r = p;
        p += (bytes + 255) & ~(size_t)255;
        return r;
    };
    f16* enc_t     = (f16*)take((size_t)32 * 196 * 512 * 2);
    f16* enc_att_h = (f16*)take((size_t)32 * 196 * 512 * 2);
    f16* W_encT    = (f16*)take((size_t)512 * 512 * 2);
    f16* W_fcT     = (f16*)take((size_t)10112 * 512 * 2);
    f16* Wdf8      = (f16*)take((size_t)512 * 1024 * 2);
    f16* Wpart8    = (f16*)take((size_t)1024 * 2048 * 2);
    f16* Wmid8     = (f16*)take((size_t)512 * 2048 * 2);
    f16* h_all     = (f16*)take((size_t)2048 * 512 * 2);
    f16* h_h       = (f16*)take((size_t)32 * 512 * 2);
    float* b_df    = (float*)take(1024 * 4);
    float* b_cat   = (float*)take(2048 * 4);
    float* mean_e  = (float*)take((size_t)32 * 512 * 4);
    float* c_st    = (float*)take((size_t)32 * 512 * 4);
    float* da_gp   = (float*)take((size_t)32 * 1024 * 4);
    float* awe2    = (float*)take((size_t)32 * 512 * 4);
    float* psum2   = (float*)take((size_t)32 * 4);
    unsigned* bar  = (unsigned*)take(2048);

    k_prep_w<<<1024, 256, 0, stream>>>(W_enc_att, W_dec_att, W_f_beta,
                                       b_dec_att, b_f_beta, b_ih, b_hh,
                                       W_encT, Wdf8, b_df, b_cat);
    k_tr_fc<<<dim3(158, 8), 256, 0, stream>>>(W_fc, W_fcT);
    k_pack_part<<<dim3(16, 32), 256, 0, stream>>>(W_ih, W_hh, Wpart8);
    k_pack_mid<<<dim3(8, 32), 256, 0, stream>>>(W_ih, Wmid8);
    k_prep_enc<<<256, 256, 0, stream>>>(encoder_out, enc_t, mean_e);
    k_h0c0<<<65, 256, 0, stream>>>(mean_e, W_init_h, b_init_h, W_init_c, b_init_c,
                                   c_st, h_h, h_all, bar);
    k_encatt<<<dim3(49, 4), 256, 0, stream>>>(enc_t, W_encT, b_enc_att, enc_att_h);
    k_loop<<<256, 512, 0, stream>>>(Wdf8, b_df, Wpart8, Wmid8, b_cat,
                                    enc_att_h, enc_t, W_full_att, emb, caps, cl,
                                    c_st, h_h, da_gp, awe2, psum2, h_all, bar);
    k_fc<<<dim3(16, 79), 256, 0, stream>>>(h_all, W_fcT, b_fc, cl, (float*)d_out);
}